// Round 2
// baseline (9336.256 us; speedup 1.0000x reference)
//
#include <hip/hip_runtime.h>
#include <hip/hip_bf16.h>

#define NN 100000
#define NE 1600000
#define NF 128
#define NG 128
#define NC 10

// ---------------- degree / norm precompute ----------------

__global__ __launch_bounds__(256) void k_deg(const int* __restrict__ dst,
                                             const float* __restrict__ ew,
                                             float* __restrict__ deg) {
    int e = blockIdx.x * 256 + threadIdx.x;
    if (e < NE) atomicAdd(&deg[dst[e]], ew[e]);
}

// deg currently holds sum of incoming edge weights; self-loop adds +1.
__global__ __launch_bounds__(256) void k_dinv(float* __restrict__ deg) {
    int i = blockIdx.x * 256 + threadIdx.x;
    if (i < NN) deg[i] = rsqrtf(deg[i] + 1.0f);
}

__global__ __launch_bounds__(256) void k_norm(const int* __restrict__ src,
                                              const int* __restrict__ dst,
                                              const float* __restrict__ ew,
                                              const float* __restrict__ dinv,
                                              float* __restrict__ norm) {
    int e = blockIdx.x * 256 + threadIdx.x;
    if (e < NE) norm[e] = dinv[src[e]] * ew[e] * dinv[dst[e]];
}

// ---------------- GEMM: out[N,128] = A[N,128] @ W[128,128] ----------------
// 8 rows per block of 256 threads; W staged in LDS (64KB + 4KB < 160KB/CU).

__global__ __launch_bounds__(256) void k_gemm128(const float* __restrict__ A,
                                                 const float* __restrict__ W,
                                                 float* __restrict__ out) {
    __shared__ float sW[128][128];   // 64 KB
    __shared__ float sA[8][128];     // 4 KB

    const float4* W4 = (const float4*)W;
    float4* sW4 = (float4*)&sW[0][0];
    for (int t = threadIdx.x; t < 128 * 128 / 4; t += 256) sW4[t] = W4[t];

    int row0 = blockIdx.x * 8;
    {
        const float4* A4 = (const float4*)(A + (size_t)row0 * NF);
        float4* sA4 = (float4*)&sA[0][0];
        sA4[threadIdx.x] = A4[threadIdx.x];
    }
    __syncthreads();

    int j  = threadIdx.x & 127;  // output column
    int i0 = threadIdx.x >> 7;   // 0..1
    float acc0 = 0.f, acc1 = 0.f, acc2 = 0.f, acc3 = 0.f;
    for (int k = 0; k < 128; ++k) {
        float w = sW[k][j];
        acc0 += sA[i0 + 0][k] * w;
        acc1 += sA[i0 + 2][k] * w;
        acc2 += sA[i0 + 4][k] * w;
        acc3 += sA[i0 + 6][k] * w;
    }
    out[(size_t)(row0 + i0 + 0) * NF + j] = acc0;
    out[(size_t)(row0 + i0 + 2) * NF + j] = acc1;
    out[(size_t)(row0 + i0 + 4) * NF + j] = acc2;
    out[(size_t)(row0 + i0 + 6) * NF + j] = acc3;
}

// ---------------- edge scatter: agg[dst] += h[src] * norm ----------------
// 32 threads per edge, float4 per thread, 8 edges per block.

__global__ __launch_bounds__(256) void k_scatter(const int* __restrict__ src,
                                                 const int* __restrict__ dst,
                                                 const float* __restrict__ norm,
                                                 const float* __restrict__ h,
                                                 float* __restrict__ agg) {
    int eid = blockIdx.x * 8 + (threadIdx.x >> 5);
    if (eid >= NE) return;
    int lane = threadIdx.x & 31;
    int s = src[eid], d = dst[eid];
    float nw = norm[eid];
    float4 v = ((const float4*)(h + (size_t)s * NF))[lane];
    float* op = agg + (size_t)d * NF + (size_t)lane * 4;
    atomicAdd(op + 0, v.x * nw);
    atomicAdd(op + 1, v.y * nw);
    atomicAdd(op + 2, v.z * nw);
    atomicAdd(op + 3, v.w * nw);
}

// ---------------- epilogue: agg = relu(agg + tmp*dinv^2 + b) ----------------

__global__ __launch_bounds__(256) void k_finish(const float* __restrict__ tmp,
                                                const float* __restrict__ dinv,
                                                const float* __restrict__ b,
                                                float* __restrict__ agg) {
    int idx = blockIdx.x * 256 + threadIdx.x;  // float4 index over N*32
    int i = idx >> 5;
    int c = idx & 31;
    float di = dinv[i];
    float d2 = di * di;
    float4 t = ((const float4*)tmp)[idx];
    float4 a = ((float4*)agg)[idx];
    float4 bb = ((const float4*)b)[c];
    a.x = fmaxf(a.x + t.x * d2 + bb.x, 0.f);
    a.y = fmaxf(a.y + t.y * d2 + bb.y, 0.f);
    a.z = fmaxf(a.z + t.z * d2 + bb.z, 0.f);
    a.w = fmaxf(a.w + t.w * d2 + bb.w, 0.f);
    ((float4*)agg)[idx] = a;
}

// ---------------- global mean pool (sum + count via atomics) ----------------

__global__ __launch_bounds__(256) void k_pool(const float* __restrict__ h,
                                              const int* __restrict__ batch,
                                              float* __restrict__ gsum,
                                              float* __restrict__ gcnt) {
    int idx = blockIdx.x * 256 + threadIdx.x;  // float4 index over N*32
    int i = idx >> 5;
    int c = idx & 31;
    int g = batch[i];
    float4 v = ((const float4*)h)[idx];
    float* gp = gsum + (size_t)g * NF + (size_t)c * 4;
    atomicAdd(gp + 0, v.x);
    atomicAdd(gp + 1, v.y);
    atomicAdd(gp + 2, v.z);
    atomicAdd(gp + 3, v.w);
    if (c == 0) atomicAdd(&gcnt[g], 1.0f);
}

// ---------------- head: 2-layer MLP + log_softmax, one block per graph ----------------

__global__ __launch_bounds__(128) void k_head(const float* __restrict__ gsum,
                                              const float* __restrict__ gcnt,
                                              const float* __restrict__ Wl1,
                                              const float* __restrict__ bl1,
                                              const float* __restrict__ Wl2,
                                              const float* __restrict__ bl2,
                                              float* __restrict__ out) {
    __shared__ float sg[128];
    __shared__ float sh[128];
    __shared__ float slog[16];
    int g = blockIdx.x;
    int t = threadIdx.x;
    float cnt = fmaxf(gcnt[g], 1.0f);
    sg[t] = gsum[(size_t)g * NF + t] / cnt;
    __syncthreads();
    float acc = bl1[t];
    for (int k = 0; k < 128; ++k) acc += sg[k] * Wl1[k * 128 + t];
    sh[t] = fmaxf(acc, 0.f);
    __syncthreads();
    if (t < NC) {
        float a = bl2[t];
        for (int k = 0; k < 128; ++k) a += sh[k] * Wl2[k * NC + t];
        slog[t] = a;
    }
    __syncthreads();
    if (t < NC) {
        float m = -1e30f;
        for (int c = 0; c < NC; ++c) m = fmaxf(m, slog[c]);
        float s = 0.f;
        for (int c = 0; c < NC; ++c) s += expf(slog[c] - m);
        out[(size_t)g * NC + t] = slog[t] - m - logf(s);
    }
}

// ---------------- launch ----------------

extern "C" void kernel_launch(void* const* d_in, const int* in_sizes, int n_in,
                              void* d_out, int out_size, void* d_ws, size_t ws_size,
                              hipStream_t stream) {
    const float* x     = (const float*)d_in[0];
    const int*   ei    = (const int*)d_in[1];
    const float* ew    = (const float*)d_in[2];
    const int*   batch = (const int*)d_in[3];
    const float* W1  = (const float*)d_in[4];
    const float* b1  = (const float*)d_in[5];
    const float* W2  = (const float*)d_in[6];
    const float* b2  = (const float*)d_in[7];
    const float* W3  = (const float*)d_in[8];
    const float* b3  = (const float*)d_in[9];
    const float* Wl1 = (const float*)d_in[10];
    const float* bl1 = (const float*)d_in[11];
    const float* Wl2 = (const float*)d_in[12];
    const float* bl2 = (const float*)d_in[13];
    float* out = (float*)d_out;

    const int* src = ei;            // edge_index[0]
    const int* dst = ei + NE;       // edge_index[1]

    // workspace carve-up (all f32), ~109 MB total
    float* bufT = (float*)d_ws;                 // NN*NF  (GEMM out)
    float* bufH = bufT + (size_t)NN * NF;       // NN*NF  (agg / layer out)
    float* dinv = bufH + (size_t)NN * NF;       // NN     (deg -> dinv in place)
    float* norm = dinv + NN;                    // NE
    float* gsum = norm + NE;                    // NG*NF
    float* gcnt = gsum + NG * NF;               // NG

    // degree + norm (once)
    hipMemsetAsync(dinv, 0, NN * sizeof(float), stream);
    k_deg<<<(NE + 255) / 256, 256, 0, stream>>>(dst, ew, dinv);
    k_dinv<<<(NN + 255) / 256, 256, 0, stream>>>(dinv);
    k_norm<<<(NE + 255) / 256, 256, 0, stream>>>(src, dst, ew, dinv, norm);

    const float* Ws[3] = {W1, W2, W3};
    const float* bs[3] = {b1, b2, b3};
    const float* in = x;
    for (int l = 0; l < 3; ++l) {
        k_gemm128<<<NN / 8, 256, 0, stream>>>(in, Ws[l], bufT);
        hipMemsetAsync(bufH, 0, (size_t)NN * NF * sizeof(float), stream);
        k_scatter<<<(NE + 7) / 8, 256, 0, stream>>>(src, dst, norm, bufT, bufH);
        k_finish<<<NN * 32 / 256, 256, 0, stream>>>(bufT, dinv, bs[l], bufH);
        in = bufH;
    }

    // global mean pool
    hipMemsetAsync(gsum, 0, (NG * NF + NG) * sizeof(float), stream);
    k_pool<<<NN * 32 / 256, 256, 0, stream>>>(bufH, batch, gsum, gcnt);

    // MLP head + log_softmax
    k_head<<<NG, 128, 0, stream>>>(gsum, gcnt, Wl1, bl1, Wl2, bl2, out);
}

// Round 3
// 943.193 us; speedup vs baseline: 9.8986x; 9.8986x over previous
//
#include <hip/hip_runtime.h>
#include <hip/hip_bf16.h>

#define NN 100000
#define NE 1600000
#define NF 128
#define NG 128
#define NC 10

#define SCAN_B 256
#define NBLK ((NN + SCAN_B - 1) / SCAN_B)   // 391

// ---------------- degree + count histogram ----------------

__global__ __launch_bounds__(256) void k_deg(const int* __restrict__ dst,
                                             const float* __restrict__ ew,
                                             float* __restrict__ deg,
                                             int* __restrict__ cnt) {
    int e = blockIdx.x * 256 + threadIdx.x;
    if (e < NE) {
        int d = dst[e];
        atomicAdd(&deg[d], ew[e]);
        atomicAdd(&cnt[d], 1);
    }
}

// deg holds sum of incoming real edge weights; self-loop adds +1.
__global__ __launch_bounds__(256) void k_dinv(float* __restrict__ deg) {
    int i = blockIdx.x * 256 + threadIdx.x;
    if (i < NN) deg[i] = rsqrtf(deg[i] + 1.0f);
}

// ---------------- exclusive scan of cnt -> rowstart (3 kernels) ----------------

__global__ __launch_bounds__(SCAN_B) void k_scan1(const int* __restrict__ cnt,
                                                  int* __restrict__ rowstart,
                                                  int* __restrict__ bsum) {
    __shared__ int s[SCAN_B];
    int i = blockIdx.x * SCAN_B + threadIdx.x;
    int v = (i < NN) ? cnt[i] : 0;
    s[threadIdx.x] = v;
    __syncthreads();
    for (int off = 1; off < SCAN_B; off <<= 1) {
        int t = (threadIdx.x >= off) ? s[threadIdx.x - off] : 0;
        __syncthreads();
        s[threadIdx.x] += t;
        __syncthreads();
    }
    if (i < NN) rowstart[i] = s[threadIdx.x] - v;   // exclusive within block
    if (threadIdx.x == SCAN_B - 1) bsum[blockIdx.x] = s[SCAN_B - 1];
}

__global__ __launch_bounds__(512) void k_scan2(int* __restrict__ bsum) {
    __shared__ int s[512];
    int v = (threadIdx.x < NBLK) ? bsum[threadIdx.x] : 0;
    s[threadIdx.x] = v;
    __syncthreads();
    for (int off = 1; off < 512; off <<= 1) {
        int t = (threadIdx.x >= off) ? s[threadIdx.x - off] : 0;
        __syncthreads();
        s[threadIdx.x] += t;
        __syncthreads();
    }
    if (threadIdx.x < NBLK) bsum[threadIdx.x] = s[threadIdx.x] - v;  // exclusive
}

__global__ __launch_bounds__(SCAN_B) void k_scan3(int* __restrict__ rowstart,
                                                  const int* __restrict__ bsum) {
    int i = blockIdx.x * SCAN_B + threadIdx.x;
    if (i < NN) rowstart[i] += bsum[blockIdx.x];
}

// ---------------- bucket edges into CSR (sorted by dst) ----------------

__global__ __launch_bounds__(256) void k_bucket(const int* __restrict__ src,
                                                const int* __restrict__ dst,
                                                const float* __restrict__ ew,
                                                const float* __restrict__ dinv,
                                                const int* __restrict__ rowstart,
                                                int* __restrict__ fill,
                                                int* __restrict__ esrc,
                                                float* __restrict__ enorm) {
    int e = blockIdx.x * 256 + threadIdx.x;
    if (e >= NE) return;
    int s = src[e], d = dst[e];
    int pos = rowstart[d] + atomicAdd(&fill[d], 1);
    esrc[pos]  = s;
    enorm[pos] = dinv[s] * ew[e] * dinv[d];
}

// ---------------- GEMM: out[N,128] = A[N,128] @ W[128,128] ----------------
// 64 rows/block, 256 threads; thread computes 8 rows x 4 cols.
// A staged in LDS (32KB), W streamed through L1/L2 (64KB, resident).

__global__ __launch_bounds__(256) void k_gemm128(const float* __restrict__ A,
                                                 const float* __restrict__ W,
                                                 float* __restrict__ out) {
    __shared__ float sA[64][128];    // 32 KB

    int row0 = blockIdx.x * 64;
    for (int t = threadIdx.x; t < 64 * 32; t += 256) {
        int r  = t >> 5;
        int c4 = t & 31;
        float4 v = make_float4(0.f, 0.f, 0.f, 0.f);
        if (row0 + r < NN) v = ((const float4*)(A + (size_t)(row0 + r) * NF))[c4];
        ((float4*)&sA[r][0])[c4] = v;
    }
    __syncthreads();

    int tj = (threadIdx.x & 31) * 4;        // col group
    int r0 = (threadIdx.x >> 5) * 8;        // first of 8 rows

    float acc[8][4] = {};
    const float4* W4 = (const float4*)W;

    for (int k = 0; k < 128; k += 4) {
        float4 w0 = W4[(size_t)(k + 0) * 32 + (tj >> 2)];
        float4 w1 = W4[(size_t)(k + 1) * 32 + (tj >> 2)];
        float4 w2 = W4[(size_t)(k + 2) * 32 + (tj >> 2)];
        float4 w3 = W4[(size_t)(k + 3) * 32 + (tj >> 2)];
#pragma unroll
        for (int i = 0; i < 8; ++i) {
            float4 a = *(const float4*)&sA[r0 + i][k];
            acc[i][0] += a.x * w0.x + a.y * w1.x + a.z * w2.x + a.w * w3.x;
            acc[i][1] += a.x * w0.y + a.y * w1.y + a.z * w2.y + a.w * w3.y;
            acc[i][2] += a.x * w0.z + a.y * w1.z + a.z * w2.z + a.w * w3.z;
            acc[i][3] += a.x * w0.w + a.y * w1.w + a.z * w2.w + a.w * w3.w;
        }
    }

#pragma unroll
    for (int i = 0; i < 8; ++i) {
        int row = row0 + r0 + i;
        if (row < NN) {
            float4 o = make_float4(acc[i][0], acc[i][1], acc[i][2], acc[i][3]);
            *(float4*)&out[(size_t)row * NF + tj] = o;
        }
    }
}

// ---------------- CSR gather + self-loop + bias + relu (fused) ----------------
// One wave (64 lanes) per node; lane owns 2 consecutive feats (float2).

__global__ __launch_bounds__(256) void k_gather(const int* __restrict__ rowstart,
                                                const int* __restrict__ cnt,
                                                const int* __restrict__ esrc,
                                                const float* __restrict__ enorm,
                                                const float* __restrict__ h,
                                                const float* __restrict__ dinv,
                                                const float* __restrict__ b,
                                                float* __restrict__ outp) {
    int node = blockIdx.x * 4 + (threadIdx.x >> 6);
    int lane = threadIdx.x & 63;
    int beg = rowstart[node];
    int n   = cnt[node];

    float ax = 0.f, ay = 0.f, bx = 0.f, by = 0.f;
    int k = 0;
    for (; k + 2 <= n; k += 2) {
        int   s0 = esrc[beg + k];
        int   s1 = esrc[beg + k + 1];
        float w0 = enorm[beg + k];
        float w1 = enorm[beg + k + 1];
        float2 v0 = ((const float2*)(h + (size_t)s0 * NF))[lane];
        float2 v1 = ((const float2*)(h + (size_t)s1 * NF))[lane];
        ax += v0.x * w0; ay += v0.y * w0;
        bx += v1.x * w1; by += v1.y * w1;
    }
    if (k < n) {
        int   s0 = esrc[beg + k];
        float w0 = enorm[beg + k];
        float2 v0 = ((const float2*)(h + (size_t)s0 * NF))[lane];
        ax += v0.x * w0; ay += v0.y * w0;
    }

    float di = dinv[node];
    float d2 = di * di;
    float2 hv = ((const float2*)(h + (size_t)node * NF))[lane];
    float2 bb = ((const float2*)b)[lane];
    float ox = fmaxf(ax + bx + hv.x * d2 + bb.x, 0.f);
    float oy = fmaxf(ay + by + hv.y * d2 + bb.y, 0.f);
    ((float2*)(outp + (size_t)node * NF))[lane] = make_float2(ox, oy);
}

// ---------------- global mean pool: sorted batch, segment accumulation ----------------
// One wave handles 16 consecutive nodes; flush atomics only on segment change.

__global__ __launch_bounds__(256) void k_pool(const float* __restrict__ h,
                                              const int* __restrict__ batch,
                                              float* __restrict__ gsum,
                                              float* __restrict__ gcnt) {
    int wid  = blockIdx.x * 4 + (threadIdx.x >> 6);
    int lane = threadIdx.x & 63;
    int n0 = wid * 16;
    if (n0 >= NN) return;

    float ax = 0.f, ay = 0.f;
    int cur = batch[n0];
    int nodes = 0;
    for (int t = 0; t < 16 && n0 + t < NN; ++t) {
        int g = batch[n0 + t];
        if (g != cur) {
            atomicAdd(&gsum[(size_t)cur * NF + lane * 2 + 0], ax);
            atomicAdd(&gsum[(size_t)cur * NF + lane * 2 + 1], ay);
            if (lane == 0) atomicAdd(&gcnt[cur], (float)nodes);
            ax = 0.f; ay = 0.f; nodes = 0; cur = g;
        }
        float2 v = ((const float2*)(h + (size_t)(n0 + t) * NF))[lane];
        ax += v.x; ay += v.y;
        ++nodes;
    }
    atomicAdd(&gsum[(size_t)cur * NF + lane * 2 + 0], ax);
    atomicAdd(&gsum[(size_t)cur * NF + lane * 2 + 1], ay);
    if (lane == 0) atomicAdd(&gcnt[cur], (float)nodes);
}

// ---------------- head: 2-layer MLP + log_softmax, one block per graph ----------------

__global__ __launch_bounds__(128) void k_head(const float* __restrict__ gsum,
                                              const float* __restrict__ gcnt,
                                              const float* __restrict__ Wl1,
                                              const float* __restrict__ bl1,
                                              const float* __restrict__ Wl2,
                                              const float* __restrict__ bl2,
                                              float* __restrict__ out) {
    __shared__ float sg[128];
    __shared__ float sh[128];
    __shared__ float slog[16];
    int g = blockIdx.x;
    int t = threadIdx.x;
    float cnt = fmaxf(gcnt[g], 1.0f);
    sg[t] = gsum[(size_t)g * NF + t] / cnt;
    __syncthreads();
    float acc = bl1[t];
    for (int k = 0; k < 128; ++k) acc += sg[k] * Wl1[k * 128 + t];
    sh[t] = fmaxf(acc, 0.f);
    __syncthreads();
    if (t < NC) {
        float a = bl2[t];
        for (int k = 0; k < 128; ++k) a += sh[k] * Wl2[k * NC + t];
        slog[t] = a;
    }
    __syncthreads();
    if (t < NC) {
        float m = -1e30f;
        for (int c = 0; c < NC; ++c) m = fmaxf(m, slog[c]);
        float s = 0.f;
        for (int c = 0; c < NC; ++c) s += expf(slog[c] - m);
        out[(size_t)g * NC + t] = slog[t] - m - logf(s);
    }
}

// ---------------- launch ----------------

extern "C" void kernel_launch(void* const* d_in, const int* in_sizes, int n_in,
                              void* d_out, int out_size, void* d_ws, size_t ws_size,
                              hipStream_t stream) {
    const float* x     = (const float*)d_in[0];
    const int*   ei    = (const int*)d_in[1];
    const float* ew    = (const float*)d_in[2];
    const int*   batch = (const int*)d_in[3];
    const float* W1  = (const float*)d_in[4];
    const float* b1  = (const float*)d_in[5];
    const float* W2  = (const float*)d_in[6];
    const float* b2  = (const float*)d_in[7];
    const float* W3  = (const float*)d_in[8];
    const float* b3  = (const float*)d_in[9];
    const float* Wl1 = (const float*)d_in[10];
    const float* bl1 = (const float*)d_in[11];
    const float* Wl2 = (const float*)d_in[12];
    const float* bl2 = (const float*)d_in[13];
    float* out = (float*)d_out;

    const int* src = ei;            // edge_index[0]
    const int* dst = ei + NE;       // edge_index[1]

    // workspace carve-up (~117 MB)
    float* bufA = (float*)d_ws;                      // NN*NF (GEMM out)
    float* bufB = bufA + (size_t)NN * NF;            // NN*NF (gather out)
    float* dinv = bufB + (size_t)NN * NF;            // NN
    float* enorm = dinv + NN;                        // NE
    float* gsum = enorm + NE;                        // NG*NF
    float* gcnt = gsum + NG * NF;                    // NG
    int* cnt      = (int*)(gcnt + NG);               // NN
    int* rowstart = cnt + NN;                        // NN
    int* fill     = rowstart + NN;                   // NN
    int* esrc     = fill + NN;                       // NE
    int* bsum     = esrc + NE;                       // NBLK

    // ---- CSR build + norm precompute (once per call) ----
    hipMemsetAsync(dinv, 0, NN * sizeof(float), stream);
    hipMemsetAsync(cnt, 0, NN * sizeof(int), stream);
    hipMemsetAsync(fill, 0, NN * sizeof(int), stream);
    k_deg<<<(NE + 255) / 256, 256, 0, stream>>>(dst, ew, dinv, cnt);
    k_dinv<<<(NN + 255) / 256, 256, 0, stream>>>(dinv);
    k_scan1<<<NBLK, SCAN_B, 0, stream>>>(cnt, rowstart, bsum);
    k_scan2<<<1, 512, 0, stream>>>(bsum);
    k_scan3<<<NBLK, SCAN_B, 0, stream>>>(rowstart, bsum);
    k_bucket<<<(NE + 255) / 256, 256, 0, stream>>>(src, dst, ew, dinv, rowstart,
                                                   fill, esrc, enorm);

    // ---- 3 GCN layers ----
    const float* Ws[3] = {W1, W2, W3};
    const float* bs[3] = {b1, b2, b3};
    const float* in = x;
    for (int l = 0; l < 3; ++l) {
        k_gemm128<<<(NN + 63) / 64, 256, 0, stream>>>(in, Ws[l], bufA);
        k_gather<<<NN / 4, 256, 0, stream>>>(rowstart, cnt, esrc, enorm,
                                             bufA, dinv, bs[l], bufB);
        in = bufB;
    }

    // ---- global mean pool ----
    hipMemsetAsync(gsum, 0, (NG * NF + NG) * sizeof(float), stream);
    k_pool<<<(NN / 16 + 3) / 4, 256, 0, stream>>>(bufB, batch, gsum, gcnt);

    // ---- MLP head + log_softmax ----
    k_head<<<NG, 128, 0, stream>>>(gsum, gcnt, Wl1, bl1, Wl2, bl2, out);
}

// Round 4
// 777.184 us; speedup vs baseline: 12.0129x; 1.2136x over previous
//
#include <hip/hip_runtime.h>
#include <hip/hip_bf16.h>

#define NN 100000
#define NE 1600000
#define NF 128
#define NG 128
#define NC 10

#define SCAN_B 256
#define NBLK ((NN + SCAN_B - 1) / SCAN_B)   // 391

typedef short short8 __attribute__((ext_vector_type(8)));
typedef float f32x4 __attribute__((ext_vector_type(4)));

__device__ inline unsigned short f2bf(float x) {
    unsigned u = __float_as_uint(x);
    u += 0x7FFF + ((u >> 16) & 1);          // round-to-nearest-even
    return (unsigned short)(u >> 16);
}
__device__ inline float bf2f(unsigned short h) {
    return __uint_as_float(((unsigned)h) << 16);
}

// ---------------- degree+count histogram: ONE packed u64 atomic per edge ----------------
// bits [63:42] = count, bits [41:0] = sum(ew) in 2^-22 fixed point.

__global__ __launch_bounds__(256) void k_deg(const int* __restrict__ dst,
                                             const float* __restrict__ ew,
                                             unsigned long long* __restrict__ packed) {
    int e = blockIdx.x * 256 + threadIdx.x;
    if (e < NE) {
        int d = dst[e];
        unsigned fx = (unsigned)__float2uint_rn(ew[e] * 4194304.0f);  // 2^22
        unsigned long long inc = (1ULL << 42) | (unsigned long long)fx;
        atomicAdd(&packed[d], inc);
    }
}

__global__ __launch_bounds__(256) void k_dinv(const unsigned long long* __restrict__ packed,
                                              float* __restrict__ dinv,
                                              int* __restrict__ cnt) {
    int i = blockIdx.x * 256 + threadIdx.x;
    if (i < NN) {
        unsigned long long v = packed[i];
        cnt[i] = (int)(v >> 42);
        float deg = (float)(v & ((1ULL << 42) - 1)) * (1.0f / 4194304.0f);
        dinv[i] = rsqrtf(deg + 1.0f);       // +1 = self-loop
    }
}

// ---------------- exclusive scan of cnt -> rowstart ----------------

__global__ __launch_bounds__(SCAN_B) void k_scan1(const int* __restrict__ cnt,
                                                  int* __restrict__ rowstart,
                                                  int* __restrict__ bsum) {
    __shared__ int s[SCAN_B];
    int i = blockIdx.x * SCAN_B + threadIdx.x;
    int v = (i < NN) ? cnt[i] : 0;
    s[threadIdx.x] = v;
    __syncthreads();
    for (int off = 1; off < SCAN_B; off <<= 1) {
        int t = (threadIdx.x >= off) ? s[threadIdx.x - off] : 0;
        __syncthreads();
        s[threadIdx.x] += t;
        __syncthreads();
    }
    if (i < NN) rowstart[i] = s[threadIdx.x] - v;
    if (threadIdx.x == SCAN_B - 1) bsum[blockIdx.x] = s[SCAN_B - 1];
}

__global__ __launch_bounds__(512) void k_scan2(int* __restrict__ bsum) {
    __shared__ int s[512];
    int v = (threadIdx.x < NBLK) ? bsum[threadIdx.x] : 0;
    s[threadIdx.x] = v;
    __syncthreads();
    for (int off = 1; off < 512; off <<= 1) {
        int t = (threadIdx.x >= off) ? s[threadIdx.x - off] : 0;
        __syncthreads();
        s[threadIdx.x] += t;
        __syncthreads();
    }
    if (threadIdx.x < NBLK) bsum[threadIdx.x] = s[threadIdx.x] - v;
}

__global__ __launch_bounds__(SCAN_B) void k_scan3(int* __restrict__ rowstart,
                                                  const int* __restrict__ bsum,
                                                  int* __restrict__ rowfill) {
    int i = blockIdx.x * SCAN_B + threadIdx.x;
    if (i < NN) {
        int v = rowstart[i] + bsum[blockIdx.x];
        rowstart[i] = v;
        rowfill[i]  = v;   // bucket's atomic cursor (rowstart preserved for gather)
    }
}

// ---------------- bucket edges into CSR: one 8B write per edge ----------------

__global__ __launch_bounds__(256) void k_bucket(const int* __restrict__ src,
                                                const int* __restrict__ dst,
                                                const float* __restrict__ ew,
                                                const float* __restrict__ dinv,
                                                int* __restrict__ rowfill,
                                                int2* __restrict__ epair) {
    int e = blockIdx.x * 256 + threadIdx.x;
    if (e >= NE) return;
    int s = src[e], d = dst[e];
    int pos = atomicAdd(&rowfill[d], 1);
    float nrm = dinv[s] * ew[e] * dinv[d];
    epair[pos] = make_int2(s, __float_as_int(nrm));
}

// ---------------- W -> transposed, XOR-swizzled bf16 hi/lo image ----------------
// image element (col j of W, k) at ushort index ((j*256 + k*2) ^ ((j&7)<<4)) / 2

__global__ __launch_bounds__(128) void k_wconv(const float* __restrict__ W0,
                                               const float* __restrict__ W1,
                                               const float* __restrict__ W2,
                                               unsigned short* __restrict__ hiimg,
                                               unsigned short* __restrict__ loimg) {
    const float* W = (blockIdx.y == 0) ? W0 : (blockIdx.y == 1) ? W1 : W2;
    int k = blockIdx.x;      // input feat (row of W)
    int j = threadIdx.x;     // output feat (col of W)
    float v = W[k * 128 + j];
    unsigned short hi = f2bf(v);
    unsigned short lo = f2bf(v - bf2f(hi));
    unsigned off = (((unsigned)j * 256u + (unsigned)k * 2u) ^ (((unsigned)(j & 7)) << 4)) >> 1;
    hiimg[(size_t)blockIdx.y * 16384 + off] = hi;
    loimg[(size_t)blockIdx.y * 16384 + off] = lo;
}

// ---------------- MFMA GEMM: out[N,128] = A[N,128] @ W[128,128] ----------------
// f32 in/out; internal bf16 hi/lo split, 3 MFMA passes (err ~2^-17).
// Block: 256 thr (4 waves), 64 rows. Wave w owns rows [w*16, w*16+16).

__global__ __launch_bounds__(256) void k_gemm_mfma(const float* __restrict__ A,
                                                   const unsigned short* __restrict__ hiimg,
                                                   const unsigned short* __restrict__ loimg,
                                                   float* __restrict__ out) {
    __shared__ unsigned short sW[2][16384];   // 64 KB: [0]=hi, [1]=lo (pre-swizzled)

    {
        f32x4* d0 = (f32x4*)&sW[0][0];
        f32x4* d1 = (f32x4*)&sW[1][0];
        const f32x4* s0 = (const f32x4*)hiimg;
        const f32x4* s1 = (const f32x4*)loimg;
        for (int t = threadIdx.x; t < 2048; t += 256) { d0[t] = s0[t]; d1[t] = s1[t]; }
    }
    __syncthreads();

    int l  = threadIdx.x & 63;
    int w  = threadIdx.x >> 6;
    int lr = l & 15;                 // A-row / B-col / D-col within tile
    int kq = l >> 4;                 // 0..3 k-chunk
    int row = blockIdx.x * 64 + w * 16 + lr;
    bool valid = row < NN;
    const float* ap = A + (size_t)row * NF;

    f32x4 acc[8];
#pragma unroll
    for (int c = 0; c < 8; ++c) acc[c] = (f32x4){0.f, 0.f, 0.f, 0.f};

#pragma unroll
    for (int kk = 0; kk < 4; ++kk) {
        float av[8];
        if (valid) {
            const f32x4* p = (const f32x4*)(ap + kk * 32 + kq * 8);
            f32x4 a0 = p[0], a1 = p[1];
            av[0] = a0.x; av[1] = a0.y; av[2] = a0.z; av[3] = a0.w;
            av[4] = a1.x; av[5] = a1.y; av[6] = a1.z; av[7] = a1.w;
        } else {
#pragma unroll
            for (int j = 0; j < 8; ++j) av[j] = 0.f;
        }
        short8 ahi, alo;
#pragma unroll
        for (int j = 0; j < 8; ++j) {
            unsigned short h = f2bf(av[j]);
            ahi[j] = (short)h;
            alo[j] = (short)f2bf(av[j] - bf2f(h));
        }
#pragma unroll
        for (int c = 0; c < 8; ++c) {
            int j = c * 16 + lr;     // B col
            unsigned off = ((unsigned)(j * 256 + kk * 64 + kq * 16)) ^ (((unsigned)(j & 7)) << 4);
            short8 bhi = *(const short8*)((const char*)&sW[0][0] + off);
            short8 blo = *(const short8*)((const char*)&sW[1][0] + off);
            acc[c] = __builtin_amdgcn_mfma_f32_16x16x32_bf16(ahi, bhi, acc[c], 0, 0, 0);
            acc[c] = __builtin_amdgcn_mfma_f32_16x16x32_bf16(alo, bhi, acc[c], 0, 0, 0);
            acc[c] = __builtin_amdgcn_mfma_f32_16x16x32_bf16(ahi, blo, acc[c], 0, 0, 0);
        }
    }

    // D: lane l, reg r -> row=(l>>4)*4+r, col=c*16+(l&15)
    int orow0 = blockIdx.x * 64 + w * 16 + kq * 4;
#pragma unroll
    for (int r = 0; r < 4; ++r) {
        int orow = orow0 + r;
        if (orow < NN) {
            float* op = out + (size_t)orow * NF + lr;
#pragma unroll
            for (int c = 0; c < 8; ++c) op[c * 16] = acc[c][r];
        }
    }
}

// ---------------- CSR gather + self-loop + bias + relu (fused) ----------------

__global__ __launch_bounds__(256) void k_gather(const int* __restrict__ rowstart,
                                                const int* __restrict__ cnt,
                                                const int2* __restrict__ epair,
                                                const float* __restrict__ h,
                                                const float* __restrict__ dinv,
                                                const float* __restrict__ b,
                                                float* __restrict__ outp) {
    int node = blockIdx.x * 4 + (threadIdx.x >> 6);
    int lane = threadIdx.x & 63;
    int beg = rowstart[node];
    int n   = cnt[node];

    float ax = 0.f, ay = 0.f, bx = 0.f, by = 0.f;
    int k = 0;
    for (; k + 2 <= n; k += 2) {
        int2 e0 = epair[beg + k];
        int2 e1 = epair[beg + k + 1];
        float w0 = __int_as_float(e0.y);
        float w1 = __int_as_float(e1.y);
        float2 v0 = ((const float2*)(h + (size_t)e0.x * NF))[lane];
        float2 v1 = ((const float2*)(h + (size_t)e1.x * NF))[lane];
        ax += v0.x * w0; ay += v0.y * w0;
        bx += v1.x * w1; by += v1.y * w1;
    }
    if (k < n) {
        int2 e0 = epair[beg + k];
        float w0 = __int_as_float(e0.y);
        float2 v0 = ((const float2*)(h + (size_t)e0.x * NF))[lane];
        ax += v0.x * w0; ay += v0.y * w0;
    }

    float di = dinv[node];
    float d2 = di * di;
    float2 hv = ((const float2*)(h + (size_t)node * NF))[lane];
    float2 bb = ((const float2*)b)[lane];
    float ox = fmaxf(ax + bx + hv.x * d2 + bb.x, 0.f);
    float oy = fmaxf(ay + by + hv.y * d2 + bb.y, 0.f);
    ((float2*)(outp + (size_t)node * NF))[lane] = make_float2(ox, oy);
}

// ---------------- global mean pool (sorted batch, segmented) ----------------

__global__ __launch_bounds__(256) void k_pool(const float* __restrict__ h,
                                              const int* __restrict__ batch,
                                              float* __restrict__ gsum,
                                              float* __restrict__ gcnt) {
    int wid  = blockIdx.x * 4 + (threadIdx.x >> 6);
    int lane = threadIdx.x & 63;
    int n0 = wid * 16;
    if (n0 >= NN) return;

    float ax = 0.f, ay = 0.f;
    int cur = batch[n0];
    int nodes = 0;
    for (int t = 0; t < 16 && n0 + t < NN; ++t) {
        int g = batch[n0 + t];
        if (g != cur) {
            atomicAdd(&gsum[(size_t)cur * NF + lane * 2 + 0], ax);
            atomicAdd(&gsum[(size_t)cur * NF + lane * 2 + 1], ay);
            if (lane == 0) atomicAdd(&gcnt[cur], (float)nodes);
            ax = 0.f; ay = 0.f; nodes = 0; cur = g;
        }
        float2 v = ((const float2*)(h + (size_t)(n0 + t) * NF))[lane];
        ax += v.x; ay += v.y;
        ++nodes;
    }
    atomicAdd(&gsum[(size_t)cur * NF + lane * 2 + 0], ax);
    atomicAdd(&gsum[(size_t)cur * NF + lane * 2 + 1], ay);
    if (lane == 0) atomicAdd(&gcnt[cur], (float)nodes);
}

// ---------------- head: MLP + log_softmax ----------------

__global__ __launch_bounds__(128) void k_head(const float* __restrict__ gsum,
                                              const float* __restrict__ gcnt,
                                              const float* __restrict__ Wl1,
                                              const float* __restrict__ bl1,
                                              const float* __restrict__ Wl2,
                                              const float* __restrict__ bl2,
                                              float* __restrict__ out) {
    __shared__ float sg[128];
    __shared__ float sh[128];
    __shared__ float slog[16];
    int g = blockIdx.x;
    int t = threadIdx.x;
    float cnt = fmaxf(gcnt[g], 1.0f);
    sg[t] = gsum[(size_t)g * NF + t] / cnt;
    __syncthreads();
    float acc = bl1[t];
    for (int k = 0; k < 128; ++k) acc += sg[k] * Wl1[k * 128 + t];
    sh[t] = fmaxf(acc, 0.f);
    __syncthreads();
    if (t < NC) {
        float a = bl2[t];
        for (int k = 0; k < 128; ++k) a += sh[k] * Wl2[k * NC + t];
        slog[t] = a;
    }
    __syncthreads();
    if (t < NC) {
        float m = -1e30f;
        for (int c = 0; c < NC; ++c) m = fmaxf(m, slog[c]);
        float s = 0.f;
        for (int c = 0; c < NC; ++c) s += expf(slog[c] - m);
        out[(size_t)g * NC + t] = slog[t] - m - logf(s);
    }
}

// ---------------- launch ----------------

extern "C" void kernel_launch(void* const* d_in, const int* in_sizes, int n_in,
                              void* d_out, int out_size, void* d_ws, size_t ws_size,
                              hipStream_t stream) {
    const float* x     = (const float*)d_in[0];
    const int*   ei    = (const int*)d_in[1];
    const float* ew    = (const float*)d_in[2];
    const int*   batch = (const int*)d_in[3];
    const float* W1  = (const float*)d_in[4];
    const float* b1  = (const float*)d_in[5];
    const float* W2  = (const float*)d_in[6];
    const float* b2  = (const float*)d_in[7];
    const float* W3  = (const float*)d_in[8];
    const float* b3  = (const float*)d_in[9];
    const float* Wl1 = (const float*)d_in[10];
    const float* bl1 = (const float*)d_in[11];
    const float* Wl2 = (const float*)d_in[12];
    const float* bl2 = (const float*)d_in[13];
    float* out = (float*)d_out;

    const int* src = ei;            // edge_index[0]
    const int* dst = ei + NE;       // edge_index[1]

    // workspace carve-up (~113 MB)
    float* bufA = (float*)d_ws;                                   // NN*NF
    float* bufB = bufA + (size_t)NN * NF;                         // NN*NF
    unsigned long long* packed = (unsigned long long*)(bufB + (size_t)NN * NF);  // NN
    int2*  epair = (int2*)(packed + NN);                          // NE
    float* dinv  = (float*)(epair + NE);                          // NN
    float* gsum  = dinv + NN;                                     // NG*NF
    float* gcnt  = gsum + NG * NF;                                // NG
    int* cnt      = (int*)(gcnt + NG);                            // NN
    int* rowstart = cnt + NN;                                     // NN
    int* rowfill  = rowstart + NN;                                // NN
    int* bsum     = rowfill + NN;                                 // 512 (padded)
    unsigned short* hiimg = (unsigned short*)(bsum + 512);        // 3*16384
    unsigned short* loimg = hiimg + 3 * 16384;                    // 3*16384

    // ---- CSR build + norms ----
    hipMemsetAsync(packed, 0, NN * sizeof(unsigned long long), stream);
    k_deg<<<(NE + 255) / 256, 256, 0, stream>>>(dst, ew, packed);
    k_dinv<<<(NN + 255) / 256, 256, 0, stream>>>(packed, dinv, cnt);
    k_scan1<<<NBLK, SCAN_B, 0, stream>>>(cnt, rowstart, bsum);
    k_scan2<<<1, 512, 0, stream>>>(bsum);
    k_scan3<<<NBLK, SCAN_B, 0, stream>>>(rowstart, bsum, rowfill);
    k_bucket<<<(NE + 255) / 256, 256, 0, stream>>>(src, dst, ew, dinv, rowfill, epair);

    // ---- W images ----
    k_wconv<<<dim3(128, 3), 128, 0, stream>>>(W1, W2, W3, hiimg, loimg);

    // ---- 3 GCN layers ----
    const float* bs[3] = {b1, b2, b3};
    const float* in = x;
    for (int l = 0; l < 3; ++l) {
        k_gemm_mfma<<<(NN + 63) / 64, 256, 0, stream>>>(in, hiimg + (size_t)l * 16384,
                                                        loimg + (size_t)l * 16384, bufA);
        k_gather<<<NN / 4, 256, 0, stream>>>(rowstart, cnt, epair, bufA, dinv, bs[l], bufB);
        in = bufB;
    }

    // ---- global mean pool ----
    hipMemsetAsync(gsum, 0, (NG * NF + NG) * sizeof(float), stream);
    k_pool<<<(NN / 16 + 3) / 4, 256, 0, stream>>>(bufB, batch, gsum, gcnt);

    // ---- head ----
    k_head<<<NG, 128, 0, stream>>>(gsum, gcnt, Wl1, bl1, Wl2, bl2, out);
}

// Round 5
// 602.922 us; speedup vs baseline: 15.4850x; 1.2890x over previous
//
#include <hip/hip_runtime.h>
#include <hip/hip_bf16.h>

#define NN 100000
#define NE 1600000
#define NF 128
#define NG 128
#define NC 10

#define SCAN_B 256
#define NBLK ((NN + SCAN_B - 1) / SCAN_B)   // 391

typedef short short8 __attribute__((ext_vector_type(8)));
typedef float f32x4 __attribute__((ext_vector_type(4)));

__device__ inline unsigned short f2bf(float x) {
    unsigned u = __float_as_uint(x);
    u += 0x7FFF + ((u >> 16) & 1);          // round-to-nearest-even
    return (unsigned short)(u >> 16);
}
__device__ inline float bf2f(unsigned short h) {
    return __uint_as_float(((unsigned)h) << 16);
}
// unpack a uint holding two bf16 (lo = feat 2l, hi = feat 2l+1)
__device__ inline float bfu_lo(unsigned v) { return __uint_as_float(v << 16); }
__device__ inline float bfu_hi(unsigned v) { return __uint_as_float(v & 0xffff0000u); }
__device__ inline unsigned bfu_pack(float lo, float hi) {
    return (unsigned)f2bf(lo) | ((unsigned)f2bf(hi) << 16);
}

// ---------------- degree+count histogram: ONE packed u64 atomic per edge ----------------
// bits [63:42] = count, bits [41:0] = sum(ew) in 2^-22 fixed point.

__global__ __launch_bounds__(256) void k_deg(const int* __restrict__ dst,
                                             const float* __restrict__ ew,
                                             unsigned long long* __restrict__ packed) {
    int e = blockIdx.x * 256 + threadIdx.x;
    if (e < NE) {
        int d = dst[e];
        unsigned fx = (unsigned)__float2uint_rn(ew[e] * 4194304.0f);  // 2^22
        unsigned long long inc = (1ULL << 42) | (unsigned long long)fx;
        atomicAdd(&packed[d], inc);
    }
}

__global__ __launch_bounds__(256) void k_dinv(const unsigned long long* __restrict__ packed,
                                              float* __restrict__ dinv,
                                              int* __restrict__ cnt) {
    int i = blockIdx.x * 256 + threadIdx.x;
    if (i < NN) {
        unsigned long long v = packed[i];
        cnt[i] = (int)(v >> 42);
        float deg = (float)(v & ((1ULL << 42) - 1)) * (1.0f / 4194304.0f);
        dinv[i] = rsqrtf(deg + 1.0f);       // +1 = self-loop
    }
}

// ---------------- exclusive scan of cnt -> rowstart ----------------

__global__ __launch_bounds__(SCAN_B) void k_scan1(const int* __restrict__ cnt,
                                                  int* __restrict__ rowstart,
                                                  int* __restrict__ bsum) {
    __shared__ int s[SCAN_B];
    int i = blockIdx.x * SCAN_B + threadIdx.x;
    int v = (i < NN) ? cnt[i] : 0;
    s[threadIdx.x] = v;
    __syncthreads();
    for (int off = 1; off < SCAN_B; off <<= 1) {
        int t = (threadIdx.x >= off) ? s[threadIdx.x - off] : 0;
        __syncthreads();
        s[threadIdx.x] += t;
        __syncthreads();
    }
    if (i < NN) rowstart[i] = s[threadIdx.x] - v;
    if (threadIdx.x == SCAN_B - 1) bsum[blockIdx.x] = s[SCAN_B - 1];
}

__global__ __launch_bounds__(512) void k_scan2(int* __restrict__ bsum) {
    __shared__ int s[512];
    int v = (threadIdx.x < NBLK) ? bsum[threadIdx.x] : 0;
    s[threadIdx.x] = v;
    __syncthreads();
    for (int off = 1; off < 512; off <<= 1) {
        int t = (threadIdx.x >= off) ? s[threadIdx.x - off] : 0;
        __syncthreads();
        s[threadIdx.x] += t;
        __syncthreads();
    }
    if (threadIdx.x < NBLK) bsum[threadIdx.x] = s[threadIdx.x] - v;
}

__global__ __launch_bounds__(SCAN_B) void k_scan3(int* __restrict__ rowstart,
                                                  const int* __restrict__ bsum,
                                                  int* __restrict__ rowfill) {
    int i = blockIdx.x * SCAN_B + threadIdx.x;
    if (i < NN) {
        int v = rowstart[i] + bsum[blockIdx.x];
        rowstart[i] = v;
        rowfill[i]  = v;
    }
}

// ---------------- bucket edges into CSR: one 8B write per edge ----------------

__global__ __launch_bounds__(256) void k_bucket(const int* __restrict__ src,
                                                const int* __restrict__ dst,
                                                const float* __restrict__ ew,
                                                const float* __restrict__ dinv,
                                                int* __restrict__ rowfill,
                                                int2* __restrict__ epair) {
    int e = blockIdx.x * 256 + threadIdx.x;
    if (e >= NE) return;
    int s = src[e], d = dst[e];
    int pos = atomicAdd(&rowfill[d], 1);
    float nrm = dinv[s] * ew[e] * dinv[d];
    epair[pos] = make_int2(s, __float_as_int(nrm));
}

// ---------------- W -> transposed, XOR-swizzled bf16 hi/lo image ----------------

__global__ __launch_bounds__(128) void k_wconv(const float* __restrict__ W0,
                                               const float* __restrict__ W1,
                                               const float* __restrict__ W2,
                                               unsigned short* __restrict__ hiimg,
                                               unsigned short* __restrict__ loimg) {
    const float* W = (blockIdx.y == 0) ? W0 : (blockIdx.y == 1) ? W1 : W2;
    int k = blockIdx.x;      // input feat (row of W)
    int j = threadIdx.x;     // output feat (col of W)
    float v = W[k * 128 + j];
    unsigned short hi = f2bf(v);
    unsigned short lo = f2bf(v - bf2f(hi));
    unsigned off = (((unsigned)j * 256u + (unsigned)k * 2u) ^ (((unsigned)(j & 7)) << 4)) >> 1;
    hiimg[(size_t)blockIdx.y * 16384 + off] = hi;
    loimg[(size_t)blockIdx.y * 16384 + off] = lo;
}

// ---------------- MFMA GEMM: out_bf16[N,128] = A[N,128] @ W[128,128] ----------------
// BF16IN=false: A is f32, hi/lo split (3 MFMA passes). BF16IN=true: A is bf16 (2 passes).
// Block: 256 thr (4 waves), 64 rows. Wave w owns rows [w*16, w*16+16).

template <bool BF16IN>
__global__ __launch_bounds__(256) void k_gemm_mfma(const void* __restrict__ Ain,
                                                   const unsigned short* __restrict__ hiimg,
                                                   const unsigned short* __restrict__ loimg,
                                                   unsigned short* __restrict__ outb) {
    __shared__ unsigned short sW[2][16384];   // 64 KB: [0]=hi, [1]=lo (pre-swizzled)
    __shared__ unsigned short sD[4][16 * 128];  // 16 KB D-repack tiles (per wave)

    {
        f32x4* d0 = (f32x4*)&sW[0][0];
        f32x4* d1 = (f32x4*)&sW[1][0];
        const f32x4* s0 = (const f32x4*)hiimg;
        const f32x4* s1 = (const f32x4*)loimg;
        for (int t = threadIdx.x; t < 2048; t += 256) { d0[t] = s0[t]; d1[t] = s1[t]; }
    }
    __syncthreads();

    int l  = threadIdx.x & 63;
    int w  = threadIdx.x >> 6;
    int lr = l & 15;                 // A-row / B-col / D-col within tile
    int kq = l >> 4;                 // 0..3 k-chunk
    int row = blockIdx.x * 64 + w * 16 + lr;
    bool valid = row < NN;

    f32x4 acc[8];
#pragma unroll
    for (int c = 0; c < 8; ++c) acc[c] = (f32x4){0.f, 0.f, 0.f, 0.f};

#pragma unroll
    for (int kk = 0; kk < 4; ++kk) {
        short8 ahi = {}, alo = {};
        if (BF16IN) {
            if (valid)
                ahi = *(const short8*)((const unsigned short*)Ain + (size_t)row * NF + kk * 32 + kq * 8);
        } else {
            float av[8];
            if (valid) {
                const f32x4* p = (const f32x4*)((const float*)Ain + (size_t)row * NF + kk * 32 + kq * 8);
                f32x4 a0 = p[0], a1 = p[1];
                av[0] = a0.x; av[1] = a0.y; av[2] = a0.z; av[3] = a0.w;
                av[4] = a1.x; av[5] = a1.y; av[6] = a1.z; av[7] = a1.w;
            } else {
#pragma unroll
                for (int j = 0; j < 8; ++j) av[j] = 0.f;
            }
#pragma unroll
            for (int j = 0; j < 8; ++j) {
                unsigned short h = f2bf(av[j]);
                ahi[j] = (short)h;
                alo[j] = (short)f2bf(av[j] - bf2f(h));
            }
        }
#pragma unroll
        for (int c = 0; c < 8; ++c) {
            int j = c * 16 + lr;     // B col
            unsigned off = ((unsigned)(j * 256 + kk * 64 + kq * 16)) ^ (((unsigned)(j & 7)) << 4);
            short8 bhi = *(const short8*)((const char*)&sW[0][0] + off);
            short8 blo = *(const short8*)((const char*)&sW[1][0] + off);
            acc[c] = __builtin_amdgcn_mfma_f32_16x16x32_bf16(ahi, bhi, acc[c], 0, 0, 0);
            if (!BF16IN)
                acc[c] = __builtin_amdgcn_mfma_f32_16x16x32_bf16(alo, bhi, acc[c], 0, 0, 0);
            acc[c] = __builtin_amdgcn_mfma_f32_16x16x32_bf16(ahi, blo, acc[c], 0, 0, 0);
        }
    }

    // D: lane l, reg r -> row=(l>>4)*4+r, col=c*16+(l&15). Repack via per-wave LDS
    // tile (wave-local: no barrier needed), then coalesced short8 row stores.
#pragma unroll
    for (int r = 0; r < 4; ++r)
#pragma unroll
        for (int c = 0; c < 8; ++c)
            sD[w][(kq * 4 + r) * 128 + c * 16 + lr] = f2bf(acc[c][r]);

    int row0w = blockIdx.x * 64 + w * 16;
#pragma unroll
    for (int i = 0; i < 4; ++i) {
        int ci = l + 64 * i;          // ushort8 chunk id: row=ci>>4, col8=ci&15
        int rr = ci >> 4, c8 = ci & 15;
        if (row0w + rr < NN)
            *(short8*)(outb + (size_t)(row0w + rr) * NF + c8 * 8) =
                *(const short8*)&sD[w][rr * 128 + c8 * 8];
    }
}

// ---------------- CSR gather (bf16 h) + self-loop + bias + relu ----------------
// One wave per node; lane owns feats (2l, 2l+1) as one packed uint.

__global__ __launch_bounds__(256) void k_gather(const int* __restrict__ rowstart,
                                                const int* __restrict__ cnt,
                                                const int2* __restrict__ epair,
                                                const unsigned short* __restrict__ h,
                                                const float* __restrict__ dinv,
                                                const float* __restrict__ b,
                                                unsigned short* __restrict__ outp) {
    int node = blockIdx.x * 4 + (threadIdx.x >> 6);
    int lane = threadIdx.x & 63;
    int beg = rowstart[node];
    int n   = cnt[node];
    const unsigned* h32 = (const unsigned*)h;   // pair index = row*64 + lane

    float ax = 0.f, ay = 0.f, bx = 0.f, by = 0.f;
    float cx = 0.f, cy = 0.f, dx = 0.f, dy = 0.f;
    int k = 0;
    for (; k + 4 <= n; k += 4) {
        int2 e0 = epair[beg + k + 0];
        int2 e1 = epair[beg + k + 1];
        int2 e2 = epair[beg + k + 2];
        int2 e3 = epair[beg + k + 3];
        unsigned v0 = h32[(size_t)e0.x * 64 + lane];
        unsigned v1 = h32[(size_t)e1.x * 64 + lane];
        unsigned v2 = h32[(size_t)e2.x * 64 + lane];
        unsigned v3 = h32[(size_t)e3.x * 64 + lane];
        float w0 = __int_as_float(e0.y), w1 = __int_as_float(e1.y);
        float w2 = __int_as_float(e2.y), w3 = __int_as_float(e3.y);
        ax += bfu_lo(v0) * w0; ay += bfu_hi(v0) * w0;
        bx += bfu_lo(v1) * w1; by += bfu_hi(v1) * w1;
        cx += bfu_lo(v2) * w2; cy += bfu_hi(v2) * w2;
        dx += bfu_lo(v3) * w3; dy += bfu_hi(v3) * w3;
    }
    for (; k < n; ++k) {
        int2 e0 = epair[beg + k];
        unsigned v0 = h32[(size_t)e0.x * 64 + lane];
        float w0 = __int_as_float(e0.y);
        ax += bfu_lo(v0) * w0; ay += bfu_hi(v0) * w0;
    }
    ax += bx + cx + dx;
    ay += by + cy + dy;

    float di = dinv[node];
    float d2 = di * di;
    unsigned hv = h32[(size_t)node * 64 + lane];
    float2 bb = ((const float2*)b)[lane];
    float ox = fmaxf(ax + bfu_lo(hv) * d2 + bb.x, 0.f);
    float oy = fmaxf(ay + bfu_hi(hv) * d2 + bb.y, 0.f);
    ((unsigned*)outp)[(size_t)node * 64 + lane] = bfu_pack(ox, oy);
}

// ---------------- global mean pool (sorted batch, segmented, bf16 in) ----------------

__global__ __launch_bounds__(256) void k_pool(const unsigned short* __restrict__ h,
                                              const int* __restrict__ batch,
                                              float* __restrict__ gsum,
                                              float* __restrict__ gcnt) {
    int wid  = blockIdx.x * 4 + (threadIdx.x >> 6);
    int lane = threadIdx.x & 63;
    int n0 = wid * 16;
    if (n0 >= NN) return;
    const unsigned* h32 = (const unsigned*)h;

    float ax = 0.f, ay = 0.f;
    int cur = batch[n0];
    int nodes = 0;
    for (int t = 0; t < 16 && n0 + t < NN; ++t) {
        int g = batch[n0 + t];
        if (g != cur) {
            atomicAdd(&gsum[(size_t)cur * NF + lane * 2 + 0], ax);
            atomicAdd(&gsum[(size_t)cur * NF + lane * 2 + 1], ay);
            if (lane == 0) atomicAdd(&gcnt[cur], (float)nodes);
            ax = 0.f; ay = 0.f; nodes = 0; cur = g;
        }
        unsigned v = h32[(size_t)(n0 + t) * 64 + lane];
        ax += bfu_lo(v); ay += bfu_hi(v);
        ++nodes;
    }
    atomicAdd(&gsum[(size_t)cur * NF + lane * 2 + 0], ax);
    atomicAdd(&gsum[(size_t)cur * NF + lane * 2 + 1], ay);
    if (lane == 0) atomicAdd(&gcnt[cur], (float)nodes);
}

// ---------------- head: MLP + log_softmax ----------------

__global__ __launch_bounds__(128) void k_head(const float* __restrict__ gsum,
                                              const float* __restrict__ gcnt,
                                              const float* __restrict__ Wl1,
                                              const float* __restrict__ bl1,
                                              const float* __restrict__ Wl2,
                                              const float* __restrict__ bl2,
                                              float* __restrict__ out) {
    __shared__ float sg[128];
    __shared__ float sh[128];
    __shared__ float slog[16];
    int g = blockIdx.x;
    int t = threadIdx.x;
    float cnt = fmaxf(gcnt[g], 1.0f);
    sg[t] = gsum[(size_t)g * NF + t] / cnt;
    __syncthreads();
    float acc = bl1[t];
    for (int k = 0; k < 128; ++k) acc += sg[k] * Wl1[k * 128 + t];
    sh[t] = fmaxf(acc, 0.f);
    __syncthreads();
    if (t < NC) {
        float a = bl2[t];
        for (int k = 0; k < 128; ++k) a += sh[k] * Wl2[k * NC + t];
        slog[t] = a;
    }
    __syncthreads();
    if (t < NC) {
        float m = -1e30f;
        for (int c = 0; c < NC; ++c) m = fmaxf(m, slog[c]);
        float s = 0.f;
        for (int c = 0; c < NC; ++c) s += expf(slog[c] - m);
        out[(size_t)g * NC + t] = slog[t] - m - logf(s);
    }
}

// ---------------- launch ----------------

extern "C" void kernel_launch(void* const* d_in, const int* in_sizes, int n_in,
                              void* d_out, int out_size, void* d_ws, size_t ws_size,
                              hipStream_t stream) {
    const float* x     = (const float*)d_in[0];
    const int*   ei    = (const int*)d_in[1];
    const float* ew    = (const float*)d_in[2];
    const int*   batch = (const int*)d_in[3];
    const float* W1  = (const float*)d_in[4];
    const float* b1  = (const float*)d_in[5];
    const float* W2  = (const float*)d_in[6];
    const float* b2  = (const float*)d_in[7];
    const float* W3  = (const float*)d_in[8];
    const float* b3  = (const float*)d_in[9];
    const float* Wl1 = (const float*)d_in[10];
    const float* bl1 = (const float*)d_in[11];
    const float* Wl2 = (const float*)d_in[12];
    const float* bl2 = (const float*)d_in[13];
    float* out = (float*)d_out;

    const int* src = ei;            // edge_index[0]
    const int* dst = ei + NE;       // edge_index[1]

    // workspace carve-up (~66 MB)
    unsigned short* bufA = (unsigned short*)d_ws;                 // NN*NF bf16
    unsigned short* bufB = bufA + (size_t)NN * NF;                // NN*NF bf16
    unsigned long long* packed = (unsigned long long*)(bufB + (size_t)NN * NF);  // NN
    int2*  epair = (int2*)(packed + NN);                          // NE
    float* dinv  = (float*)(epair + NE);                          // NN
    float* gsum  = dinv + NN;                                     // NG*NF
    float* gcnt  = gsum + NG * NF;                                // NG
    int* cnt      = (int*)(gcnt + NG);                            // NN
    int* rowstart = cnt + NN;                                     // NN
    int* rowfill  = rowstart + NN;                                // NN
    int* bsum     = rowfill + NN;                                 // 512 (padded)
    unsigned short* hiimg = (unsigned short*)(bsum + 512);        // 3*16384
    unsigned short* loimg = hiimg + 3 * 16384;                    // 3*16384

    // ---- CSR build + norms ----
    hipMemsetAsync(packed, 0, NN * sizeof(unsigned long long), stream);
    k_deg<<<(NE + 255) / 256, 256, 0, stream>>>(dst, ew, packed);
    k_dinv<<<(NN + 255) / 256, 256, 0, stream>>>(packed, dinv, cnt);
    k_scan1<<<NBLK, SCAN_B, 0, stream>>>(cnt, rowstart, bsum);
    k_scan2<<<1, 512, 0, stream>>>(bsum);
    k_scan3<<<NBLK, SCAN_B, 0, stream>>>(rowstart, bsum, rowfill);
    k_bucket<<<(NE + 255) / 256, 256, 0, stream>>>(src, dst, ew, dinv, rowfill, epair);

    // ---- W images ----
    k_wconv<<<dim3(128, 3), 128, 0, stream>>>(W1, W2, W3, hiimg, loimg);

    // ---- 3 GCN layers ----
    k_gemm_mfma<false><<<(NN + 63) / 64, 256, 0, stream>>>(x, hiimg, loimg, bufA);
    k_gather<<<NN / 4, 256, 0, stream>>>(rowstart, cnt, epair, bufA, dinv, b1, bufB);
    k_gemm_mfma<true><<<(NN + 63) / 64, 256, 0, stream>>>(bufB, hiimg + 16384, loimg + 16384, bufA);
    k_gather<<<NN / 4, 256, 0, stream>>>(rowstart, cnt, epair, bufA, dinv, b2, bufB);
    k_gemm_mfma<true><<<(NN + 63) / 64, 256, 0, stream>>>(bufB, hiimg + 32768, loimg + 32768, bufA);
    k_gather<<<NN / 4, 256, 0, stream>>>(rowstart, cnt, epair, bufA, dinv, b3, bufB);

    // ---- global mean pool ----
    hipMemsetAsync(gsum, 0, (NG * NF + NG) * sizeof(float), stream);
    k_pool<<<(NN / 16 + 3) / 4, 256, 0, stream>>>(bufB, batch, gsum, gcnt);

    // ---- head ----
    k_head<<<NG, 128, 0, stream>>>(gsum, gcnt, Wl1, bl1, Wl2, bl2, out);
}

// Round 6
// 536.037 us; speedup vs baseline: 17.4172x; 1.1248x over previous
//
#include <hip/hip_runtime.h>
#include <hip/hip_bf16.h>

#define NN 100000
#define NE 1600000
#define NF 128
#define NG 128
#define NC 10

#define NCH 782        // 128-node chunks: 782*128 = 100096 >= NN
#define PBLK 128       // partition blocks
#define EPB 12500      // edges per partition block (128*12500 = NE exactly)

typedef short short8 __attribute__((ext_vector_type(8)));
typedef float f32x4 __attribute__((ext_vector_type(4)));

__device__ inline unsigned short f2bf(float x) {
    unsigned u = __float_as_uint(x);
    u += 0x7FFF + ((u >> 16) & 1);          // round-to-nearest-even
    return (unsigned short)(u >> 16);
}
__device__ inline float bf2f(unsigned short h) {
    return __uint_as_float(((unsigned)h) << 16);
}
__device__ inline float bfu_lo(unsigned v) { return __uint_as_float(v << 16); }
__device__ inline float bfu_hi(unsigned v) { return __uint_as_float(v & 0xffff0000u); }
__device__ inline unsigned bfu_pack(float lo, float hi) {
    return (unsigned)f2bf(lo) | ((unsigned)f2bf(hi) << 16);
}

// ================= CSR build: two-level counting sort, NO global atomics =================

// P1: per-block LDS histogram over 782 coarse chunks
__global__ __launch_bounds__(256) void k_phist(const int* __restrict__ dst,
                                               unsigned* __restrict__ mat) {
    __shared__ unsigned lh[NCH];
    for (int i = threadIdx.x; i < NCH; i += 256) lh[i] = 0;
    __syncthreads();
    int base = blockIdx.x * EPB;
    for (int i = threadIdx.x; i < EPB; i += 256)
        atomicAdd(&lh[dst[base + i] >> 7], 1u);
    __syncthreads();
    for (int i = threadIdx.x; i < NCH; i += 256)
        mat[(size_t)blockIdx.x * NCH + i] = lh[i];
}

// P2a: per-column exclusive scan of mat[128][NCH]; column sums -> ctot
__global__ __launch_bounds__(PBLK) void k_cscan(unsigned* __restrict__ mat,
                                                unsigned* __restrict__ ctot) {
    __shared__ unsigned s[PBLK];
    int ch = blockIdx.x;
    int t  = threadIdx.x;
    unsigned v = mat[(size_t)t * NCH + ch];
    s[t] = v;
    __syncthreads();
    for (int off = 1; off < PBLK; off <<= 1) {
        unsigned u = (t >= off) ? s[t - off] : 0;
        __syncthreads();
        s[t] += u;
        __syncthreads();
    }
    mat[(size_t)t * NCH + ch] = s[t] - v;
    if (t == PBLK - 1) ctot[ch] = s[t];
}

// P2b: exclusive scan of chunk totals -> cbase[NCH+1]
__global__ __launch_bounds__(1024) void k_cbase(const unsigned* __restrict__ ctot,
                                                unsigned* __restrict__ cbase) {
    __shared__ unsigned s[1024];
    int t = threadIdx.x;
    unsigned v = (t < NCH) ? ctot[t] : 0;
    s[t] = v;
    __syncthreads();
    for (int off = 1; off < 1024; off <<= 1) {
        unsigned u = (t >= off) ? s[t - off] : 0;
        __syncthreads();
        s[t] += u;
        __syncthreads();
    }
    if (t < NCH) cbase[t] = s[t] - v;
    if (t == NCH - 1) cbase[NCH] = s[t];
}

// P3: scatter edges into chunk-partitioned order; positions from LDS cursors.
// payload: meta = src | (dstLow7 << 20), plus raw ew bits.
__global__ __launch_bounds__(256) void k_pscat(const int* __restrict__ src,
                                               const int* __restrict__ dst,
                                               const float* __restrict__ ew,
                                               const unsigned* __restrict__ mat,
                                               const unsigned* __restrict__ cbase,
                                               int2* __restrict__ eparts) {
    __shared__ unsigned cur[NCH];
    for (int i = threadIdx.x; i < NCH; i += 256)
        cur[i] = cbase[i] + mat[(size_t)blockIdx.x * NCH + i];
    __syncthreads();
    int base = blockIdx.x * EPB;
    for (int i = threadIdx.x; i < EPB; i += 256) {
        int e = base + i;
        int d = dst[e], s = src[e];
        float w = ew[e];
        unsigned pos = atomicAdd(&cur[d >> 7], 1u);   // LDS atomic
        eparts[pos] = make_int2(s | ((d & 127) << 20), __float_as_int(w));
    }
}

// P4: one block per chunk: per-node hist + ew-sums (=> deg/dinv FREE), LDS scan
// -> rowstart/cnt, then in-window scatter to exact CSR order.
__global__ __launch_bounds__(256) void k_csort(const unsigned* __restrict__ cbase,
                                               const int2* __restrict__ eparts,
                                               int2* __restrict__ efinal,
                                               int* __restrict__ rowstart,
                                               int* __restrict__ cnt,
                                               float* __restrict__ dinv) {
    __shared__ unsigned nh[128];
    __shared__ float    ws[128];
    __shared__ unsigned sc[128];
    __shared__ unsigned cur[128];
    int ch = blockIdx.x;
    unsigned beg = cbase[ch], end = cbase[ch + 1];
    int t = threadIdx.x;
    if (t < 128) { nh[t] = 0; ws[t] = 0.f; }
    __syncthreads();
    for (unsigned i = beg + t; i < end; i += 256) {
        int2 ep = eparts[i];
        int n = (ep.x >> 20) & 127;
        atomicAdd(&nh[n], 1u);
        atomicAdd(&ws[n], __int_as_float(ep.y));
    }
    __syncthreads();
    unsigned v = (t < 128) ? nh[t] : 0;
    if (t < 128) sc[t] = v;
    __syncthreads();
    for (int off = 1; off < 128; off <<= 1) {
        unsigned u = (t >= off && t < 128) ? sc[t - off] : 0;
        __syncthreads();
        if (t < 128) sc[t] += u;
        __syncthreads();
    }
    if (t < 128) {
        int node = ch * 128 + t;
        if (node < NN) {
            unsigned rs = beg + sc[t] - v;
            rowstart[node] = (int)rs;
            cnt[node]      = (int)v;
            dinv[node]     = rsqrtf(ws[t] + 1.0f);   // +1 = self-loop
            cur[t] = rs;
        }
    }
    __syncthreads();
    for (unsigned i = beg + t; i < end; i += 256) {
        int2 ep = eparts[i];
        int n = (ep.x >> 20) & 127;
        unsigned pos = atomicAdd(&cur[n], 1u);       // LDS atomic
        efinal[pos] = ep;
    }
}

// P5: in-place (src,ew) -> (src, norm); dinv is 400 KB, L2-resident.
__global__ __launch_bounds__(256) void k_norm2(const unsigned* __restrict__ cbase,
                                               const float* __restrict__ dinv,
                                               int2* __restrict__ efinal) {
    int ch = blockIdx.x;
    unsigned beg = cbase[ch], end = cbase[ch + 1];
    for (unsigned i = beg + threadIdx.x; i < end; i += 256) {
        int2 ep = efinal[i];
        int s = ep.x & 0xFFFFF;                 // src (<2^17)
        int d = ch * 128 + ((ep.x >> 20) & 127);
        float nrm = dinv[s] * __int_as_float(ep.y) * dinv[d];
        efinal[i] = make_int2(s, __float_as_int(nrm));
    }
}

// ---------------- W -> transposed, XOR-swizzled bf16 hi/lo image ----------------

__global__ __launch_bounds__(128) void k_wconv(const float* __restrict__ W0,
                                               const float* __restrict__ W1,
                                               const float* __restrict__ W2,
                                               unsigned short* __restrict__ hiimg,
                                               unsigned short* __restrict__ loimg) {
    const float* W = (blockIdx.y == 0) ? W0 : (blockIdx.y == 1) ? W1 : W2;
    int k = blockIdx.x;
    int j = threadIdx.x;
    float v = W[k * 128 + j];
    unsigned short hi = f2bf(v);
    unsigned short lo = f2bf(v - bf2f(hi));
    unsigned off = (((unsigned)j * 256u + (unsigned)k * 2u) ^ (((unsigned)(j & 7)) << 4)) >> 1;
    hiimg[(size_t)blockIdx.y * 16384 + off] = hi;
    loimg[(size_t)blockIdx.y * 16384 + off] = lo;
}

// ---------------- MFMA GEMM: out_bf16[N,128] = A[N,128] @ W[128,128] ----------------

template <bool BF16IN>
__global__ __launch_bounds__(256) void k_gemm_mfma(const void* __restrict__ Ain,
                                                   const unsigned short* __restrict__ hiimg,
                                                   const unsigned short* __restrict__ loimg,
                                                   unsigned short* __restrict__ outb) {
    __shared__ unsigned short sW[2][16384];     // 64 KB pre-swizzled hi/lo
    __shared__ unsigned short sD[4][16 * 128];  // 16 KB per-wave D repack

    {
        f32x4* d0 = (f32x4*)&sW[0][0];
        f32x4* d1 = (f32x4*)&sW[1][0];
        const f32x4* s0 = (const f32x4*)hiimg;
        const f32x4* s1 = (const f32x4*)loimg;
        for (int t = threadIdx.x; t < 2048; t += 256) { d0[t] = s0[t]; d1[t] = s1[t]; }
    }
    __syncthreads();

    int l  = threadIdx.x & 63;
    int w  = threadIdx.x >> 6;
    int lr = l & 15;
    int kq = l >> 4;
    int row = blockIdx.x * 64 + w * 16 + lr;
    bool valid = row < NN;

    f32x4 acc[8];
#pragma unroll
    for (int c = 0; c < 8; ++c) acc[c] = (f32x4){0.f, 0.f, 0.f, 0.f};

#pragma unroll
    for (int kk = 0; kk < 4; ++kk) {
        short8 ahi = {}, alo = {};
        if (BF16IN) {
            if (valid)
                ahi = *(const short8*)((const unsigned short*)Ain + (size_t)row * NF + kk * 32 + kq * 8);
        } else {
            float av[8];
            if (valid) {
                const f32x4* p = (const f32x4*)((const float*)Ain + (size_t)row * NF + kk * 32 + kq * 8);
                f32x4 a0 = p[0], a1 = p[1];
                av[0] = a0.x; av[1] = a0.y; av[2] = a0.z; av[3] = a0.w;
                av[4] = a1.x; av[5] = a1.y; av[6] = a1.z; av[7] = a1.w;
            } else {
#pragma unroll
                for (int j = 0; j < 8; ++j) av[j] = 0.f;
            }
#pragma unroll
            for (int j = 0; j < 8; ++j) {
                unsigned short h = f2bf(av[j]);
                ahi[j] = (short)h;
                alo[j] = (short)f2bf(av[j] - bf2f(h));
            }
        }
#pragma unroll
        for (int c = 0; c < 8; ++c) {
            int j = c * 16 + lr;
            unsigned off = ((unsigned)(j * 256 + kk * 64 + kq * 16)) ^ (((unsigned)(j & 7)) << 4);
            short8 bhi = *(const short8*)((const char*)&sW[0][0] + off);
            short8 blo = *(const short8*)((const char*)&sW[1][0] + off);
            acc[c] = __builtin_amdgcn_mfma_f32_16x16x32_bf16(ahi, bhi, acc[c], 0, 0, 0);
            if (!BF16IN)
                acc[c] = __builtin_amdgcn_mfma_f32_16x16x32_bf16(alo, bhi, acc[c], 0, 0, 0);
            acc[c] = __builtin_amdgcn_mfma_f32_16x16x32_bf16(ahi, blo, acc[c], 0, 0, 0);
        }
    }

#pragma unroll
    for (int r = 0; r < 4; ++r)
#pragma unroll
        for (int c = 0; c < 8; ++c)
            sD[w][(kq * 4 + r) * 128 + c * 16 + lr] = f2bf(acc[c][r]);

    int row0w = blockIdx.x * 64 + w * 16;
#pragma unroll
    for (int i = 0; i < 4; ++i) {
        int ci = l + 64 * i;
        int rr = ci >> 4, c8 = ci & 15;
        if (row0w + rr < NN)
            *(short8*)(outb + (size_t)(row0w + rr) * NF + c8 * 8) =
                *(const short8*)&sD[w][rr * 128 + c8 * 8];
    }
}

// ---------------- CSR gather (bf16 h) + self-loop + bias + relu ----------------

__global__ __launch_bounds__(256) void k_gather(const int* __restrict__ rowstart,
                                                const int* __restrict__ cnt,
                                                const int2* __restrict__ epair,
                                                const unsigned short* __restrict__ h,
                                                const float* __restrict__ dinv,
                                                const float* __restrict__ b,
                                                unsigned short* __restrict__ outp) {
    int node = blockIdx.x * 4 + (threadIdx.x >> 6);
    int lane = threadIdx.x & 63;
    int beg = rowstart[node];
    int n   = cnt[node];
    const unsigned* h32 = (const unsigned*)h;

    float ax = 0.f, ay = 0.f, bx = 0.f, by = 0.f;
    float cx = 0.f, cy = 0.f, dx = 0.f, dy = 0.f;
    int k = 0;
    for (; k + 4 <= n; k += 4) {
        int2 e0 = epair[beg + k + 0];
        int2 e1 = epair[beg + k + 1];
        int2 e2 = epair[beg + k + 2];
        int2 e3 = epair[beg + k + 3];
        unsigned v0 = h32[(size_t)e0.x * 64 + lane];
        unsigned v1 = h32[(size_t)e1.x * 64 + lane];
        unsigned v2 = h32[(size_t)e2.x * 64 + lane];
        unsigned v3 = h32[(size_t)e3.x * 64 + lane];
        float w0 = __int_as_float(e0.y), w1 = __int_as_float(e1.y);
        float w2 = __int_as_float(e2.y), w3 = __int_as_float(e3.y);
        ax += bfu_lo(v0) * w0; ay += bfu_hi(v0) * w0;
        bx += bfu_lo(v1) * w1; by += bfu_hi(v1) * w1;
        cx += bfu_lo(v2) * w2; cy += bfu_hi(v2) * w2;
        dx += bfu_lo(v3) * w3; dy += bfu_hi(v3) * w3;
    }
    for (; k < n; ++k) {
        int2 e0 = epair[beg + k];
        unsigned v0 = h32[(size_t)e0.x * 64 + lane];
        float w0 = __int_as_float(e0.y);
        ax += bfu_lo(v0) * w0; ay += bfu_hi(v0) * w0;
    }
    ax += bx + cx + dx;
    ay += by + cy + dy;

    float di = dinv[node];
    float d2 = di * di;
    unsigned hv = h32[(size_t)node * 64 + lane];
    float2 bb = ((const float2*)b)[lane];
    float ox = fmaxf(ax + bfu_lo(hv) * d2 + bb.x, 0.f);
    float oy = fmaxf(ay + bfu_hi(hv) * d2 + bb.y, 0.f);
    ((unsigned*)outp)[(size_t)node * 64 + lane] = bfu_pack(ox, oy);
}

// ---------------- global mean pool (sorted batch, segmented, bf16 in) ----------------

__global__ __launch_bounds__(256) void k_pool(const unsigned short* __restrict__ h,
                                              const int* __restrict__ batch,
                                              float* __restrict__ gsum,
                                              float* __restrict__ gcnt) {
    int wid  = blockIdx.x * 4 + (threadIdx.x >> 6);
    int lane = threadIdx.x & 63;
    int n0 = wid * 16;
    if (n0 >= NN) return;
    const unsigned* h32 = (const unsigned*)h;

    float ax = 0.f, ay = 0.f;
    int cur = batch[n0];
    int nodes = 0;
    for (int t = 0; t < 16 && n0 + t < NN; ++t) {
        int g = batch[n0 + t];
        if (g != cur) {
            atomicAdd(&gsum[(size_t)cur * NF + lane * 2 + 0], ax);
            atomicAdd(&gsum[(size_t)cur * NF + lane * 2 + 1], ay);
            if (lane == 0) atomicAdd(&gcnt[cur], (float)nodes);
            ax = 0.f; ay = 0.f; nodes = 0; cur = g;
        }
        unsigned v = h32[(size_t)(n0 + t) * 64 + lane];
        ax += bfu_lo(v); ay += bfu_hi(v);
        ++nodes;
    }
    atomicAdd(&gsum[(size_t)cur * NF + lane * 2 + 0], ax);
    atomicAdd(&gsum[(size_t)cur * NF + lane * 2 + 1], ay);
    if (lane == 0) atomicAdd(&gcnt[cur], (float)nodes);
}

// ---------------- head: MLP + log_softmax ----------------

__global__ __launch_bounds__(128) void k_head(const float* __restrict__ gsum,
                                              const float* __restrict__ gcnt,
                                              const float* __restrict__ Wl1,
                                              const float* __restrict__ bl1,
                                              const float* __restrict__ Wl2,
                                              const float* __restrict__ bl2,
                                              float* __restrict__ out) {
    __shared__ float sg[128];
    __shared__ float sh[128];
    __shared__ float slog[16];
    int g = blockIdx.x;
    int t = threadIdx.x;
    float cntv = fmaxf(gcnt[g], 1.0f);
    sg[t] = gsum[(size_t)g * NF + t] / cntv;
    __syncthreads();
    float acc = bl1[t];
    for (int k = 0; k < 128; ++k) acc += sg[k] * Wl1[k * 128 + t];
    sh[t] = fmaxf(acc, 0.f);
    __syncthreads();
    if (t < NC) {
        float a = bl2[t];
        for (int k = 0; k < 128; ++k) a += sh[k] * Wl2[k * NC + t];
        slog[t] = a;
    }
    __syncthreads();
    if (t < NC) {
        float m = -1e30f;
        for (int c = 0; c < NC; ++c) m = fmaxf(m, slog[c]);
        float s = 0.f;
        for (int c = 0; c < NC; ++c) s += expf(slog[c] - m);
        out[(size_t)g * NC + t] = slog[t] - m - logf(s);
    }
}

// ---------------- launch ----------------

extern "C" void kernel_launch(void* const* d_in, const int* in_sizes, int n_in,
                              void* d_out, int out_size, void* d_ws, size_t ws_size,
                              hipStream_t stream) {
    const float* x     = (const float*)d_in[0];
    const int*   ei    = (const int*)d_in[1];
    const float* ew    = (const float*)d_in[2];
    const int*   batch = (const int*)d_in[3];
    const float* W1  = (const float*)d_in[4];
    const float* b1  = (const float*)d_in[5];
    const float* W2  = (const float*)d_in[6];
    const float* b2  = (const float*)d_in[7];
    const float* W3  = (const float*)d_in[8];
    const float* b3  = (const float*)d_in[9];
    const float* Wl1 = (const float*)d_in[10];
    const float* bl1 = (const float*)d_in[11];
    const float* Wl2 = (const float*)d_in[12];
    const float* bl2 = (const float*)d_in[13];
    float* out = (float*)d_out;

    const int* src = ei;            // edge_index[0]
    const int* dst = ei + NE;       // edge_index[1]

    // workspace carve-up (~79 MB)
    unsigned short* bufA = (unsigned short*)d_ws;                 // NN*NF bf16
    unsigned short* bufB = bufA + (size_t)NN * NF;                // NN*NF bf16
    int2*  eparts = (int2*)(bufB + (size_t)NN * NF);              // NE
    int2*  efinal = eparts + NE;                                  // NE
    unsigned* mat   = (unsigned*)(efinal + NE);                   // PBLK*NCH
    unsigned* ctot  = mat + (size_t)PBLK * NCH;                   // NCH
    unsigned* cbase = ctot + NCH;                                 // NCH+1 (pad 2)
    float* dinv = (float*)(cbase + NCH + 2);                      // NN
    float* gsum = dinv + NN;                                      // NG*NF
    float* gcnt = gsum + NG * NF;                                 // NG
    int* cnt      = (int*)(gcnt + NG);                            // NN
    int* rowstart = cnt + NN;                                     // NN
    unsigned short* hiimg = (unsigned short*)(rowstart + NN);     // 3*16384
    unsigned short* loimg = hiimg + 3 * 16384;                    // 3*16384

    // ---- CSR build (no global atomics) ----
    k_phist<<<PBLK, 256, 0, stream>>>(dst, mat);
    k_cscan<<<NCH, PBLK, 0, stream>>>(mat, ctot);
    k_cbase<<<1, 1024, 0, stream>>>(ctot, cbase);
    k_pscat<<<PBLK, 256, 0, stream>>>(src, dst, ew, mat, cbase, eparts);
    k_csort<<<NCH, 256, 0, stream>>>(cbase, eparts, efinal, rowstart, cnt, dinv);
    k_norm2<<<NCH, 256, 0, stream>>>(cbase, dinv, efinal);

    // ---- W images ----
    k_wconv<<<dim3(128, 3), 128, 0, stream>>>(W1, W2, W3, hiimg, loimg);

    // ---- 3 GCN layers ----
    k_gemm_mfma<false><<<(NN + 63) / 64, 256, 0, stream>>>(x, hiimg, loimg, bufA);
    k_gather<<<NN / 4, 256, 0, stream>>>(rowstart, cnt, efinal, bufA, dinv, b1, bufB);
    k_gemm_mfma<true><<<(NN + 63) / 64, 256, 0, stream>>>(bufB, hiimg + 16384, loimg + 16384, bufA);
    k_gather<<<NN / 4, 256, 0, stream>>>(rowstart, cnt, efinal, bufA, dinv, b2, bufB);
    k_gemm_mfma<true><<<(NN + 63) / 64, 256, 0, stream>>>(bufB, hiimg + 32768, loimg + 32768, bufA);
    k_gather<<<NN / 4, 256, 0, stream>>>(rowstart, cnt, efinal, bufA, dinv, b3, bufB);

    // ---- global mean pool ----
    hipMemsetAsync(gsum, 0, (NG * NF + NG) * sizeof(float), stream);
    k_pool<<<(NN / 16 + 3) / 4, 256, 0, stream>>>(bufB, batch, gsum, gcnt);

    // ---- head ----
    k_head<<<NG, 128, 0, stream>>>(gsum, gcnt, Wl1, bl1, Wl2, bl2, out);
}

// Round 8
// 524.164 us; speedup vs baseline: 17.8117x; 1.0227x over previous
//
#include <hip/hip_runtime.h>
#include <hip/hip_bf16.h>

#define NN 100000
#define NE 1600000
#define NF 128
#define NG 128
#define NC 10

#define NCH 782        // 128-node chunks: 782*128 = 100096 >= NN
#define PBLK 128       // partition blocks
#define EPB 12500      // edges per partition block (128*12500 = NE exactly)

typedef short short8 __attribute__((ext_vector_type(8)));
typedef float f32x4 __attribute__((ext_vector_type(4)));

__device__ inline unsigned short f2bf(float x) {
    unsigned u = __float_as_uint(x);
    u += 0x7FFF + ((u >> 16) & 1);          // round-to-nearest-even
    return (unsigned short)(u >> 16);
}
__device__ inline float bf2f(unsigned short h) {
    return __uint_as_float(((unsigned)h) << 16);
}
__device__ inline float bfu_lo(unsigned v) { return __uint_as_float(v << 16); }
__device__ inline float bfu_hi(unsigned v) { return __uint_as_float(v & 0xffff0000u); }
__device__ inline unsigned bfu_pack(float lo, float hi) {
    return (unsigned)f2bf(lo) | ((unsigned)f2bf(hi) << 16);
}

// ================= CSR build: two-level counting sort, NO global atomics =================

__global__ __launch_bounds__(256) void k_phist(const int* __restrict__ dst,
                                               unsigned* __restrict__ mat) {
    __shared__ unsigned lh[NCH];
    for (int i = threadIdx.x; i < NCH; i += 256) lh[i] = 0;
    __syncthreads();
    int base = blockIdx.x * EPB;
    for (int i = threadIdx.x; i < EPB; i += 256)
        atomicAdd(&lh[dst[base + i] >> 7], 1u);
    __syncthreads();
    for (int i = threadIdx.x; i < NCH; i += 256)
        mat[(size_t)blockIdx.x * NCH + i] = lh[i];
}

__global__ __launch_bounds__(PBLK) void k_cscan(unsigned* __restrict__ mat,
                                                unsigned* __restrict__ ctot) {
    __shared__ unsigned s[PBLK];
    int ch = blockIdx.x;
    int t  = threadIdx.x;
    unsigned v = mat[(size_t)t * NCH + ch];
    s[t] = v;
    __syncthreads();
    for (int off = 1; off < PBLK; off <<= 1) {
        unsigned u = (t >= off) ? s[t - off] : 0;
        __syncthreads();
        s[t] += u;
        __syncthreads();
    }
    mat[(size_t)t * NCH + ch] = s[t] - v;
    if (t == PBLK - 1) ctot[ch] = s[t];
}

__global__ __launch_bounds__(1024) void k_cbase(const unsigned* __restrict__ ctot,
                                                unsigned* __restrict__ cbase) {
    __shared__ unsigned s[1024];
    int t = threadIdx.x;
    unsigned v = (t < NCH) ? ctot[t] : 0;
    s[t] = v;
    __syncthreads();
    for (int off = 1; off < 1024; off <<= 1) {
        unsigned u = (t >= off) ? s[t - off] : 0;
        __syncthreads();
        s[t] += u;
        __syncthreads();
    }
    if (t < NCH) cbase[t] = s[t] - v;
    if (t == NCH - 1) cbase[NCH] = s[t];
}

__global__ __launch_bounds__(256) void k_pscat(const int* __restrict__ src,
                                               const int* __restrict__ dst,
                                               const float* __restrict__ ew,
                                               const unsigned* __restrict__ mat,
                                               const unsigned* __restrict__ cbase,
                                               int2* __restrict__ eparts) {
    __shared__ unsigned cur[NCH];
    for (int i = threadIdx.x; i < NCH; i += 256)
        cur[i] = cbase[i] + mat[(size_t)blockIdx.x * NCH + i];
    __syncthreads();
    int base = blockIdx.x * EPB;
    for (int i = threadIdx.x; i < EPB; i += 256) {
        int e = base + i;
        int d = dst[e], s = src[e];
        float w = ew[e];
        unsigned pos = atomicAdd(&cur[d >> 7], 1u);   // LDS atomic
        eparts[pos] = make_int2(s | ((d & 127) << 20), __float_as_int(w));
    }
}

__global__ __launch_bounds__(256) void k_csort(const unsigned* __restrict__ cbase,
                                               const int2* __restrict__ eparts,
                                               int2* __restrict__ efinal,
                                               int* __restrict__ rowstart,
                                               int* __restrict__ cnt,
                                               float* __restrict__ dinv) {
    __shared__ unsigned nh[128];
    __shared__ float    ws[128];
    __shared__ unsigned sc[128];
    __shared__ unsigned cur[128];
    int ch = blockIdx.x;
    unsigned beg = cbase[ch], end = cbase[ch + 1];
    int t = threadIdx.x;
    if (t < 128) { nh[t] = 0; ws[t] = 0.f; }
    __syncthreads();
    for (unsigned i = beg + t; i < end; i += 256) {
        int2 ep = eparts[i];
        int n = (ep.x >> 20) & 127;
        atomicAdd(&nh[n], 1u);
        atomicAdd(&ws[n], __int_as_float(ep.y));
    }
    __syncthreads();
    unsigned v = (t < 128) ? nh[t] : 0;
    if (t < 128) sc[t] = v;
    __syncthreads();
    for (int off = 1; off < 128; off <<= 1) {
        unsigned u = (t >= off && t < 128) ? sc[t - off] : 0;
        __syncthreads();
        if (t < 128) sc[t] += u;
        __syncthreads();
    }
    if (t < 128) {
        int node = ch * 128 + t;
        if (node < NN) {
            unsigned rs = beg + sc[t] - v;
            rowstart[node] = (int)rs;
            cnt[node]      = (int)v;
            dinv[node]     = rsqrtf(ws[t] + 1.0f);   // +1 = self-loop
            cur[t] = rs;
        }
    }
    __syncthreads();
    for (unsigned i = beg + t; i < end; i += 256) {
        int2 ep = eparts[i];
        int n = (ep.x >> 20) & 127;
        unsigned pos = atomicAdd(&cur[n], 1u);       // LDS atomic
        efinal[pos] = ep;
    }
}

__global__ __launch_bounds__(256) void k_norm2(const unsigned* __restrict__ cbase,
                                               const float* __restrict__ dinv,
                                               int2* __restrict__ efinal) {
    int ch = blockIdx.x;
    unsigned beg = cbase[ch], end = cbase[ch + 1];
    for (unsigned i = beg + threadIdx.x; i < end; i += 256) {
        int2 ep = efinal[i];
        int s = ep.x & 0xFFFFF;
        int d = ch * 128 + ((ep.x >> 20) & 127);
        float nrm = dinv[s] * __int_as_float(ep.y) * dinv[d];
        efinal[i] = make_int2(s, __float_as_int(nrm));
    }
}

// ---------------- W -> transposed, XOR-swizzled bf16 hi/lo image ----------------

__global__ __launch_bounds__(128) void k_wconv(const float* __restrict__ W0,
                                               const float* __restrict__ W1,
                                               const float* __restrict__ W2,
                                               unsigned short* __restrict__ hiimg,
                                               unsigned short* __restrict__ loimg) {
    const float* W = (blockIdx.y == 0) ? W0 : (blockIdx.y == 1) ? W1 : W2;
    int k = blockIdx.x;
    int j = threadIdx.x;
    float v = W[k * 128 + j];
    unsigned short hi = f2bf(v);
    unsigned short lo = f2bf(v - bf2f(hi));
    unsigned off = (((unsigned)j * 256u + (unsigned)k * 2u) ^ (((unsigned)(j & 7)) << 4)) >> 1;
    hiimg[(size_t)blockIdx.y * 16384 + off] = hi;
    loimg[(size_t)blockIdx.y * 16384 + off] = lo;
}

// ---------------- MFMA GEMM: out_bf16[N,128] = A[N,128] @ W[128,128] ----------------

template <bool BF16IN>
__global__ __launch_bounds__(256) void k_gemm_mfma(const void* __restrict__ Ain,
                                                   const unsigned short* __restrict__ hiimg,
                                                   const unsigned short* __restrict__ loimg,
                                                   unsigned short* __restrict__ outb) {
    __shared__ unsigned short sW[2][16384];     // 64 KB pre-swizzled hi/lo
    __shared__ unsigned short sD[4][16 * 128];  // 16 KB per-wave D repack

    {
        f32x4* d0 = (f32x4*)&sW[0][0];
        f32x4* d1 = (f32x4*)&sW[1][0];
        const f32x4* s0 = (const f32x4*)hiimg;
        const f32x4* s1 = (const f32x4*)loimg;
        for (int t = threadIdx.x; t < 2048; t += 256) { d0[t] = s0[t]; d1[t] = s1[t]; }
    }
    __syncthreads();

    int l  = threadIdx.x & 63;
    int w  = threadIdx.x >> 6;
    int lr = l & 15;
    int kq = l >> 4;
    int row = blockIdx.x * 64 + w * 16 + lr;
    bool valid = row < NN;

    f32x4 acc[8];
#pragma unroll
    for (int c = 0; c < 8; ++c) acc[c] = (f32x4){0.f, 0.f, 0.f, 0.f};

#pragma unroll
    for (int kk = 0; kk < 4; ++kk) {
        short8 ahi = {}, alo = {};
        if (BF16IN) {
            if (valid)
                ahi = *(const short8*)((const unsigned short*)Ain + (size_t)row * NF + kk * 32 + kq * 8);
        } else {
            float av[8];
            if (valid) {
                const f32x4* p = (const f32x4*)((const float*)Ain + (size_t)row * NF + kk * 32 + kq * 8);
                f32x4 a0 = p[0], a1 = p[1];
                av[0] = a0.x; av[1] = a0.y; av[2] = a0.z; av[3] = a0.w;
                av[4] = a1.x; av[5] = a1.y; av[6] = a1.z; av[7] = a1.w;
            } else {
#pragma unroll
                for (int j = 0; j < 8; ++j) av[j] = 0.f;
            }
#pragma unroll
            for (int j = 0; j < 8; ++j) {
                unsigned short h = f2bf(av[j]);
                ahi[j] = (short)h;
                alo[j] = (short)f2bf(av[j] - bf2f(h));
            }
        }
#pragma unroll
        for (int c = 0; c < 8; ++c) {
            int j = c * 16 + lr;
            unsigned off = ((unsigned)(j * 256 + kk * 64 + kq * 16)) ^ (((unsigned)(j & 7)) << 4);
            short8 bhi = *(const short8*)((const char*)&sW[0][0] + off);
            short8 blo = *(const short8*)((const char*)&sW[1][0] + off);
            acc[c] = __builtin_amdgcn_mfma_f32_16x16x32_bf16(ahi, bhi, acc[c], 0, 0, 0);
            if (!BF16IN)
                acc[c] = __builtin_amdgcn_mfma_f32_16x16x32_bf16(alo, bhi, acc[c], 0, 0, 0);
            acc[c] = __builtin_amdgcn_mfma_f32_16x16x32_bf16(ahi, blo, acc[c], 0, 0, 0);
        }
    }

#pragma unroll
    for (int r = 0; r < 4; ++r)
#pragma unroll
        for (int c = 0; c < 8; ++c)
            sD[w][(kq * 4 + r) * 128 + c * 16 + lr] = f2bf(acc[c][r]);

    int row0w = blockIdx.x * 64 + w * 16;
#pragma unroll
    for (int i = 0; i < 4; ++i) {
        int ci = l + 64 * i;
        int rr = ci >> 4, c8 = ci & 15;
        if (row0w + rr < NN)
            *(short8*)(outb + (size_t)(row0w + rr) * NF + c8 * 8) =
                *(const short8*)&sD[w][rr * 128 + c8 * 8];
    }
}

// ---------------- CSR gather (bf16 h) + self-loop + bias + relu ----------------
// One wave per node; lane owns feats (2l, 2l+1). Unroll 8: 8 outstanding
// row-gathers per lane to cover L2/L3 latency (theory: latency-bound).

__global__ __launch_bounds__(256) void k_gather(const int* __restrict__ rowstart,
                                                const int* __restrict__ cnt,
                                                const int2* __restrict__ epair,
                                                const unsigned short* __restrict__ h,
                                                const float* __restrict__ dinv,
                                                const float* __restrict__ b,
                                                unsigned short* __restrict__ outp) {
    int node = blockIdx.x * 4 + (threadIdx.x >> 6);
    int lane = threadIdx.x & 63;
    int beg = rowstart[node];
    int n   = cnt[node];
    const unsigned* h32 = (const unsigned*)h;

    float sx0 = 0.f, sy0 = 0.f, sx1 = 0.f, sy1 = 0.f;
    float sx2 = 0.f, sy2 = 0.f, sx3 = 0.f, sy3 = 0.f;
    int k = 0;
    for (; k + 8 <= n; k += 8) {
        int2 e0 = epair[beg + k + 0];
        int2 e1 = epair[beg + k + 1];
        int2 e2 = epair[beg + k + 2];
        int2 e3 = epair[beg + k + 3];
        int2 e4 = epair[beg + k + 4];
        int2 e5 = epair[beg + k + 5];
        int2 e6 = epair[beg + k + 6];
        int2 e7 = epair[beg + k + 7];
        unsigned v0 = h32[(size_t)e0.x * 64 + lane];
        unsigned v1 = h32[(size_t)e1.x * 64 + lane];
        unsigned v2 = h32[(size_t)e2.x * 64 + lane];
        unsigned v3 = h32[(size_t)e3.x * 64 + lane];
        unsigned v4 = h32[(size_t)e4.x * 64 + lane];
        unsigned v5 = h32[(size_t)e5.x * 64 + lane];
        unsigned v6 = h32[(size_t)e6.x * 64 + lane];
        unsigned v7 = h32[(size_t)e7.x * 64 + lane];
        float w0 = __int_as_float(e0.y), w1 = __int_as_float(e1.y);
        float w2 = __int_as_float(e2.y), w3 = __int_as_float(e3.y);
        float w4 = __int_as_float(e4.y), w5 = __int_as_float(e5.y);
        float w6 = __int_as_float(e6.y), w7 = __int_as_float(e7.y);
        sx0 += bfu_lo(v0) * w0; sy0 += bfu_hi(v0) * w0;
        sx1 += bfu_lo(v1) * w1; sy1 += bfu_hi(v1) * w1;
        sx2 += bfu_lo(v2) * w2; sy2 += bfu_hi(v2) * w2;
        sx3 += bfu_lo(v3) * w3; sy3 += bfu_hi(v3) * w3;
        sx0 += bfu_lo(v4) * w4; sy0 += bfu_hi(v4) * w4;
        sx1 += bfu_lo(v5) * w5; sy1 += bfu_hi(v5) * w5;
        sx2 += bfu_lo(v6) * w6; sy2 += bfu_hi(v6) * w6;
        sx3 += bfu_lo(v7) * w7; sy3 += bfu_hi(v7) * w7;
    }
    for (; k + 4 <= n; k += 4) {
        int2 e0 = epair[beg + k + 0];
        int2 e1 = epair[beg + k + 1];
        int2 e2 = epair[beg + k + 2];
        int2 e3 = epair[beg + k + 3];
        unsigned v0 = h32[(size_t)e0.x * 64 + lane];
        unsigned v1 = h32[(size_t)e1.x * 64 + lane];
        unsigned v2 = h32[(size_t)e2.x * 64 + lane];
        unsigned v3 = h32[(size_t)e3.x * 64 + lane];
        float w0 = __int_as_float(e0.y), w1 = __int_as_float(e1.y);
        float w2 = __int_as_float(e2.y), w3 = __int_as_float(e3.y);
        sx0 += bfu_lo(v0) * w0; sy0 += bfu_hi(v0) * w0;
        sx1 += bfu_lo(v1) * w1; sy1 += bfu_hi(v1) * w1;
        sx2 += bfu_lo(v2) * w2; sy2 += bfu_hi(v2) * w2;
        sx3 += bfu_lo(v3) * w3; sy3 += bfu_hi(v3) * w3;
    }
    for (; k < n; ++k) {
        int2 e0 = epair[beg + k];
        unsigned v0 = h32[(size_t)e0.x * 64 + lane];
        float w0 = __int_as_float(e0.y);
        sx0 += bfu_lo(v0) * w0; sy0 += bfu_hi(v0) * w0;
    }
    float ax = (sx0 + sx1) + (sx2 + sx3);
    float ay = (sy0 + sy1) + (sy2 + sy3);

    float di = dinv[node];
    float d2 = di * di;
    unsigned hv = h32[(size_t)node * 64 + lane];
    float2 bb = ((const float2*)b)[lane];
    float ox = fmaxf(ax + bfu_lo(hv) * d2 + bb.x, 0.f);
    float oy = fmaxf(ay + bfu_hi(hv) * d2 + bb.y, 0.f);
    ((unsigned*)outp)[(size_t)node * 64 + lane] = bfu_pack(ox, oy);
}

// ---------------- global mean pool (sorted batch, segmented, bf16 in) ----------------

__global__ __launch_bounds__(256) void k_pool(const unsigned short* __restrict__ h,
                                              const int* __restrict__ batch,
                                              float* __restrict__ gsum,
                                              float* __restrict__ gcnt) {
    int wid  = blockIdx.x * 4 + (threadIdx.x >> 6);
    int lane = threadIdx.x & 63;
    int n0 = wid * 16;
    if (n0 >= NN) return;
    const unsigned* h32 = (const unsigned*)h;

    float ax = 0.f, ay = 0.f;
    int cur = batch[n0];
    int nodes = 0;
    for (int t = 0; t < 16 && n0 + t < NN; ++t) {
        int g = batch[n0 + t];
        if (g != cur) {
            atomicAdd(&gsum[(size_t)cur * NF + lane * 2 + 0], ax);
            atomicAdd(&gsum[(size_t)cur * NF + lane * 2 + 1], ay);
            if (lane == 0) atomicAdd(&gcnt[cur], (float)nodes);
            ax = 0.f; ay = 0.f; nodes = 0; cur = g;
        }
        unsigned v = h32[(size_t)(n0 + t) * 64 + lane];
        ax += bfu_lo(v); ay += bfu_hi(v);
        ++nodes;
    }
    atomicAdd(&gsum[(size_t)cur * NF + lane * 2 + 0], ax);
    atomicAdd(&gsum[(size_t)cur * NF + lane * 2 + 1], ay);
    if (lane == 0) atomicAdd(&gcnt[cur], (float)nodes);
}

// ---------------- head: MLP + log_softmax ----------------

__global__ __launch_bounds__(128) void k_head(const float* __restrict__ gsum,
                                              const float* __restrict__ gcnt,
                                              const float* __restrict__ Wl1,
                                              const float* __restrict__ bl1,
                                              const float* __restrict__ Wl2,
                                              const float* __restrict__ bl2,
                                              float* __restrict__ out) {
    __shared__ float sg[128];
    __shared__ float sh[128];
    __shared__ float slog[16];
    int g = blockIdx.x;
    int t = threadIdx.x;
    float cntv = fmaxf(gcnt[g], 1.0f);
    sg[t] = gsum[(size_t)g * NF + t] / cntv;
    __syncthreads();
    float acc = bl1[t];
    for (int k = 0; k < 128; ++k) acc += sg[k] * Wl1[k * 128 + t];
    sh[t] = fmaxf(acc, 0.f);
    __syncthreads();
    if (t < NC) {
        float a = bl2[t];
        for (int k = 0; k < 128; ++k) a += sh[k] * Wl2[k * NC + t];
        slog[t] = a;
    }
    __syncthreads();
    if (t < NC) {
        float m = -1e30f;
        for (int c = 0; c < NC; ++c) m = fmaxf(m, slog[c]);
        float s = 0.f;
        for (int c = 0; c < NC; ++c) s += expf(slog[c] - m);
        out[(size_t)g * NC + t] = slog[t] - m - logf(s);
    }
}

// ---------------- launch ----------------

extern "C" void kernel_launch(void* const* d_in, const int* in_sizes, int n_in,
                              void* d_out, int out_size, void* d_ws, size_t ws_size,
                              hipStream_t stream) {
    const float* x     = (const float*)d_in[0];
    const int*   ei    = (const int*)d_in[1];
    const float* ew    = (const float*)d_in[2];
    const int*   batch = (const int*)d_in[3];
    const float* W1  = (const float*)d_in[4];
    const float* b1  = (const float*)d_in[5];
    const float* W2  = (const float*)d_in[6];
    const float* b2  = (const float*)d_in[7];
    const float* W3  = (const float*)d_in[8];
    const float* b3  = (const float*)d_in[9];
    const float* Wl1 = (const float*)d_in[10];
    const float* bl1 = (const float*)d_in[11];
    const float* Wl2 = (const float*)d_in[12];
    const float* bl2 = (const float*)d_in[13];
    float* out = (float*)d_out;

    const int* src = ei;            // edge_index[0]
    const int* dst = ei + NE;       // edge_index[1]

    // workspace carve-up (~79 MB)
    unsigned short* bufA = (unsigned short*)d_ws;                 // NN*NF bf16
    unsigned short* bufB = bufA + (size_t)NN * NF;                // NN*NF bf16
    int2*  eparts = (int2*)(bufB + (size_t)NN * NF);              // NE
    int2*  efinal = eparts + NE;                                  // NE
    unsigned* mat   = (unsigned*)(efinal + NE);                   // PBLK*NCH
    unsigned* ctot  = mat + (size_t)PBLK * NCH;                   // NCH
    unsigned* cbase = ctot + NCH;                                 // NCH+1 (pad 2)
    float* dinv = (float*)(cbase + NCH + 2);                      // NN
    float* gsum = dinv + NN;                                      // NG*NF
    float* gcnt = gsum + NG * NF;                                 // NG
    int* cnt      = (int*)(gcnt + NG);                            // NN
    int* rowstart = cnt + NN;                                     // NN
    unsigned short* hiimg = (unsigned short*)(rowstart + NN);     // 3*16384
    unsigned short* loimg = hiimg + 3 * 16384;                    // 3*16384

    // ---- CSR build (no global atomics) ----
    k_phist<<<PBLK, 256, 0, stream>>>(dst, mat);
    k_cscan<<<NCH, PBLK, 0, stream>>>(mat, ctot);
    k_cbase<<<1, 1024, 0, stream>>>(ctot, cbase);
    k_pscat<<<PBLK, 256, 0, stream>>>(src, dst, ew, mat, cbase, eparts);
    k_csort<<<NCH, 256, 0, stream>>>(cbase, eparts, efinal, rowstart, cnt, dinv);
    k_norm2<<<NCH, 256, 0, stream>>>(cbase, dinv, efinal);

    // ---- W images ----
    k_wconv<<<dim3(128, 3), 128, 0, stream>>>(W1, W2, W3, hiimg, loimg);

    // ---- 3 GCN layers ----
    k_gemm_mfma<false><<<(NN + 63) / 64, 256, 0, stream>>>(x, hiimg, loimg, bufA);
    k_gather<<<NN / 4, 256, 0, stream>>>(rowstart, cnt, efinal, bufA, dinv, b1, bufB);
    k_gemm_mfma<true><<<(NN + 63) / 64, 256, 0, stream>>>(bufB, hiimg + 16384, loimg + 16384, bufA);
    k_gather<<<NN / 4, 256, 0, stream>>>(rowstart, cnt, efinal, bufA, dinv, b2, bufB);
    k_gemm_mfma<true><<<(NN + 63) / 64, 256, 0, stream>>>(bufB, hiimg + 32768, loimg + 32768, bufA);
    k_gather<<<NN / 4, 256, 0, stream>>>(rowstart, cnt, efinal, bufA, dinv, b3, bufB);

    // ---- global mean pool ----
    hipMemsetAsync(gsum, 0, (NG * NF + NG) * sizeof(float), stream);
    k_pool<<<(NN / 16 + 3) / 4, 256, 0, stream>>>(bufB, batch, gsum, gcnt);

    // ---- head ----
    k_head<<<NG, 128, 0, stream>>>(gsum, gcnt, Wl1, bl1, Wl2, bl2, out);
}